// Round 2
// baseline (205.844 us; speedup 1.0000x reference)
//
#include <hip/hip_runtime.h>
#include <hip/hip_bf16.h>
#include <cstdint>

typedef unsigned short u16;
typedef __attribute__((ext_vector_type(8))) short short8;
typedef __attribute__((ext_vector_type(8))) float f32x8;
typedef __attribute__((ext_vector_type(4))) float f32x4;

#define MFMA(a, b, c) __builtin_amdgcn_mfma_f32_16x16x32_bf16((a), (b), (c), 0, 0, 0)

// B=2, S=4096, E=128, NH=2, HD=64, CIN=64, COUT=64
#define SEQ 4096

static __device__ __forceinline__ u16 f2b(float f) {
    union { float f; uint32_t i; } c; c.f = f;
    uint32_t r = c.i + 0x7FFF + ((c.i >> 16) & 1);   // RNE f32->bf16
    return (u16)(r >> 16);
}
static __device__ __forceinline__ short8 ld8(const u16* p) {
    return *reinterpret_cast<const short8*>(p);
}

// ---- K0: Wc = Wout(64x128) @ Wo(128x128) (bf16), bc = bo @ Wout^T + bout (f32);
//          convert Wcp/Wq/Wk/Wv f32 -> bf16 into ws ----
__global__ void k_prep(const float* __restrict__ Wo, const float* __restrict__ bo,
                       const float* __restrict__ Wout, const float* __restrict__ bout,
                       const float* __restrict__ Wcp, const float* __restrict__ Wq,
                       const float* __restrict__ Wk, const float* __restrict__ Wv,
                       u16* __restrict__ Wc, float* __restrict__ bc,
                       u16* __restrict__ Wcp_b, u16* __restrict__ Wq_b,
                       u16* __restrict__ Wk_b, u16* __restrict__ Wv_b) {
    int idx = blockIdx.x * 256 + threadIdx.x;
    if (idx < 8192) {
        int co = idx >> 7, e = idx & 127;
        float s = 0.f;
        for (int k = 0; k < 128; k++)
            s += Wout[co * 128 + k] * Wo[k * 128 + e];
        Wc[idx] = f2b(s);
    } else if (idx < 8256) {
        int co = idx - 8192;
        float s = bout[co];
        for (int k = 0; k < 128; k++)
            s += bo[k] * Wout[co * 128 + k];
        bc[co] = s;
    } else if (idx < 16448) {
        int i = idx - 8256;  Wcp_b[i] = f2b(Wcp[i]);
    } else if (idx < 32832) {
        int i = idx - 16448; Wq_b[i] = f2b(Wq[i]);
    } else if (idx < 49216) {
        int i = idx - 32832; Wk_b[i] = f2b(Wk[i]);
    } else if (idx < 65600) {
        int i = idx - 49216; Wv_b[i] = f2b(Wv[i]);
    }
}

// ---- K1: xf[b][s][e] = sum_c x[b][c][s]*Wcp[e][c] + bcp[e] + pos[s][e] ----
// grid 128 (b * 64 sblocks), 256 thr. LDS-transpose x block (f32->bf16), then MFMA.
__global__ __launch_bounds__(256) void k_embed(const float* __restrict__ x,
                                               const u16* __restrict__ Wcp,
                                               const float* __restrict__ bcp,
                                               const float* __restrict__ pos,
                                               u16* __restrict__ xf) {
    __shared__ __align__(16) u16 xT[64][72];
    int blk = blockIdx.x;
    int b = blk >> 6, sb = (blk & 63) * 64;
    int t = threadIdx.x, w = t >> 6, l = t & 63, lc = l & 15, lg = l >> 4;

    const float* src = x + ((size_t)b * 64 + l) * SEQ + sb + w * 16;
    f32x8 a0 = *reinterpret_cast<const f32x8*>(src);
    f32x8 a1 = *reinterpret_cast<const f32x8*>(src + 8);
#pragma unroll
    for (int j = 0; j < 8; j++) {
        xT[w * 16 + j][l] = f2b(a0[j]);
        xT[w * 16 + 8 + j][l] = f2b(a1[j]);
    }
    __syncthreads();

    short8 af[2];
    af[0] = ld8(&xT[w * 16 + lc][lg * 8]);
    af[1] = ld8(&xT[w * 16 + lc][32 + lg * 8]);

#pragma unroll
    for (int nt = 0; nt < 8; nt++) {
        f32x4 acc = {0.f, 0.f, 0.f, 0.f};
#pragma unroll
        for (int ks = 0; ks < 2; ks++) {
            short8 bfr = ld8(Wcp + (nt * 16 + lc) * 64 + ks * 32 + lg * 8);
            acc = MFMA(af[ks], bfr, acc);
        }
        int e = nt * 16 + lc;
        float be = bcp[e];
#pragma unroll
        for (int r = 0; r < 4; r++) {
            int sr = sb + w * 16 + lg * 4 + r;
            float v = acc[r] + be + pos[(size_t)sr * 128 + e];
            xf[((size_t)b * SEQ + sr) * 128 + e] = f2b(v);
        }
    }
}

// ---- K2: Q/K/V = xf @ W^T, split heads, layout (B, NH, S, HD). Q pre-scaled. ----
// grid 384 = 3 * (2*64 sblocks)
__global__ __launch_bounds__(256) void k_qkv(const u16* __restrict__ xf,
                                             const u16* __restrict__ Wq,
                                             const u16* __restrict__ Wk,
                                             const u16* __restrict__ Wv,
                                             u16* __restrict__ Q, u16* __restrict__ K,
                                             u16* __restrict__ V) {
    int blk = blockIdx.x;
    int which = blk / 128, rb = blk % 128;
    const u16* W = (which == 0) ? Wq : (which == 1) ? Wk : Wv;
    u16* dst = (which == 0) ? Q : (which == 1) ? K : V;
    float scl = (which == 0) ? 0.125f : 1.0f;  // 1/sqrt(64), exact
    int b = rb >> 6, sb = (rb & 63) * 64;
    int t = threadIdx.x, w = t >> 6, l = t & 63, lc = l & 15, lg = l >> 4;

    short8 af[4];
#pragma unroll
    for (int ks = 0; ks < 4; ks++)
        af[ks] = ld8(xf + ((size_t)b * SEQ + sb + w * 16 + lc) * 128 + ks * 32 + lg * 8);

#pragma unroll
    for (int nt = 0; nt < 8; nt++) {
        f32x4 acc = {0.f, 0.f, 0.f, 0.f};
#pragma unroll
        for (int ks = 0; ks < 4; ks++) {
            short8 bfr = ld8(W + (nt * 16 + lc) * 128 + ks * 32 + lg * 8);
            acc = MFMA(af[ks], bfr, acc);
        }
        int e = nt * 16 + lc, h = e >> 6, d = e & 63;
#pragma unroll
        for (int r = 0; r < 4; r++) {
            int sr = sb + w * 16 + lg * 4 + r;
            dst[(((size_t)b * 2 + h) * SEQ + sr) * 64 + d] = f2b(acc[r] * scl);
        }
    }
}

// ---- K3: flash attention per (b,h,qblock64). 4 waves x 16 q-rows. ----
__global__ __launch_bounds__(256) void k_attn(const u16* __restrict__ Q,
                                              const u16* __restrict__ K,
                                              const u16* __restrict__ V,
                                              u16* __restrict__ O) {
    __shared__ __align__(16) u16 Vt[64][72];      // V^T tile: [d][key]
    __shared__ __align__(16) u16 Pl[4][16][72];   // per-wave P: [qrow][key]
    int blk = blockIdx.x;
    int bh = blk >> 6, qb = (blk & 63) * 64;
    int b = bh >> 1, h = bh & 1;
    const u16* Qp = Q + (size_t)bh * SEQ * 64;
    const u16* Kp = K + (size_t)bh * SEQ * 64;
    const u16* Vp = V + (size_t)bh * SEQ * 64;
    int t = threadIdx.x, w = t >> 6, l = t & 63, lc = l & 15, lg = l >> 4;

    short8 qa[2];
    qa[0] = ld8(Qp + (size_t)(qb + w * 16 + lc) * 64 + lg * 8);
    qa[1] = ld8(Qp + (size_t)(qb + w * 16 + lc) * 64 + 32 + lg * 8);

    f32x4 oacc[4];
    float m[4], ls[4];
#pragma unroll
    for (int i = 0; i < 4; i++) {
        oacc[i] = (f32x4){0.f, 0.f, 0.f, 0.f};
        m[i] = -INFINITY;
        ls[i] = 0.f;
    }

    for (int kb = 0; kb < 64; kb++) {
        int k0 = kb * 64;
        __syncthreads();  // Vt reads from previous iter done
        // stage V^T: wave w handles d-chunk w*16..w*16+15, lane = key
        const u16* vsrc = Vp + (size_t)(k0 + l) * 64 + w * 16;
        short8 v0 = ld8(vsrc), v1 = ld8(vsrc + 8);
#pragma unroll
        for (int j = 0; j < 8; j++) {
            Vt[w * 16 + j][l] = (u16)v0[j];
            Vt[w * 16 + 8 + j][l] = (u16)v1[j];
        }
        __syncthreads();

        // scores: S = Q K^T (Q pre-scaled)
        f32x4 sc[4];
#pragma unroll
        for (int nt = 0; nt < 4; nt++) {
            sc[nt] = (f32x4){0.f, 0.f, 0.f, 0.f};
#pragma unroll
            for (int ks = 0; ks < 2; ks++) {
                short8 kf = ld8(Kp + (size_t)(k0 + nt * 16 + lc) * 64 + ks * 32 + lg * 8);
                sc[nt] = MFMA(qa[ks], kf, sc[nt]);
            }
        }

        // online softmax per row (row = lg*4 + r, cols spread over 16 lanes x 4 nt)
#pragma unroll
        for (int r = 0; r < 4; r++) {
            float mx = fmaxf(fmaxf(sc[0][r], sc[1][r]), fmaxf(sc[2][r], sc[3][r]));
            mx = fmaxf(mx, __shfl_xor(mx, 1));
            mx = fmaxf(mx, __shfl_xor(mx, 2));
            mx = fmaxf(mx, __shfl_xor(mx, 4));
            mx = fmaxf(mx, __shfl_xor(mx, 8));
            float mn = fmaxf(m[r], mx);
            float corr = __expf(m[r] - mn);  // m=-inf first iter -> 0
            float rs = 0.f;
#pragma unroll
            for (int nt = 0; nt < 4; nt++) {
                float p = __expf(sc[nt][r] - mn);
                rs += p;
                Pl[w][lg * 4 + r][nt * 16 + lc] = f2b(p);
            }
            rs += __shfl_xor(rs, 1);
            rs += __shfl_xor(rs, 2);
            rs += __shfl_xor(rs, 4);
            rs += __shfl_xor(rs, 8);
            ls[r] = ls[r] * corr + rs;
            m[r] = mn;
#pragma unroll
            for (int nt = 0; nt < 4; nt++) oacc[nt][r] *= corr;
        }

        // O += P @ V
#pragma unroll
        for (int ks = 0; ks < 2; ks++) {
            short8 pa = ld8(&Pl[w][lc][ks * 32 + lg * 8]);
#pragma unroll
            for (int dt = 0; dt < 4; dt++) {
                short8 vf = ld8(&Vt[dt * 16 + lc][ks * 32 + lg * 8]);
                oacc[dt] = MFMA(pa, vf, oacc[dt]);
            }
        }
    }

    // epilogue: O layout (B, S, 128) with head offset
#pragma unroll
    for (int dt = 0; dt < 4; dt++) {
#pragma unroll
        for (int r = 0; r < 4; r++) {
            int sr = qb + w * 16 + lg * 4 + r;
            O[((size_t)b * SEQ + sr) * 128 + h * 64 + dt * 16 + lc] =
                f2b(oacc[dt][r] / ls[r]);
        }
    }
}

// ---- K4: out[b][co][s] = O[b][s][:] . Wc[co][:] + bc[co] + gate*x[b][co][s] ----
// grid 128. Wave w owns co-tile w*16; D cols = s (coalesced stores).
__global__ __launch_bounds__(256) void k_out(const u16* __restrict__ O,
                                             const u16* __restrict__ Wc,
                                             const float* __restrict__ bc,
                                             const float* __restrict__ x,
                                             const float* __restrict__ gate,
                                             float* __restrict__ out) {
    int blk = blockIdx.x;
    int b = blk >> 6, sb = (blk & 63) * 64;
    int t = threadIdx.x, w = t >> 6, l = t & 63, lc = l & 15, lg = l >> 4;
    float g = gate[0];

    short8 af[4];
#pragma unroll
    for (int ks = 0; ks < 4; ks++)
        af[ks] = ld8(Wc + (w * 16 + lc) * 128 + ks * 32 + lg * 8);

#pragma unroll
    for (int st = 0; st < 4; st++) {
        f32x4 acc = {0.f, 0.f, 0.f, 0.f};
#pragma unroll
        for (int ks = 0; ks < 4; ks++) {
            short8 bfr = ld8(O + ((size_t)b * SEQ + sb + st * 16 + lc) * 128 + ks * 32 + lg * 8);
            acc = MFMA(af[ks], bfr, acc);
        }
#pragma unroll
        for (int r = 0; r < 4; r++) {
            int co = w * 16 + lg * 4 + r;
            int s = sb + st * 16 + lc;
            size_t idx = ((size_t)b * 64 + co) * SEQ + s;
            out[idx] = acc[r] + bc[co] + g * x[idx];
        }
    }
}

extern "C" void kernel_launch(void* const* d_in, const int* in_sizes, int n_in,
                              void* d_out, int out_size, void* d_ws, size_t ws_size,
                              hipStream_t stream) {
    const float* x    = (const float*)d_in[0];
    const float* Wcp  = (const float*)d_in[1];
    const float* bcp  = (const float*)d_in[2];
    const float* Wq   = (const float*)d_in[3];
    const float* Wk   = (const float*)d_in[4];
    const float* Wv   = (const float*)d_in[5];
    const float* Wo   = (const float*)d_in[6];
    const float* bo   = (const float*)d_in[7];
    const float* Wout = (const float*)d_in[8];
    const float* bout = (const float*)d_in[9];
    const float* pos  = (const float*)d_in[10];
    const float* gate = (const float*)d_in[11];

    char* ws = (char*)d_ws;
    u16*   xf  = (u16*)(ws);                           // 2 MB  (2,4096,128) bf16
    u16*   Qb  = (u16*)(ws + (2u << 20));              // 2 MB  (2,2,4096,64) bf16
    u16*   Kb  = (u16*)(ws + (4u << 20));              // 2 MB
    u16*   Vb  = (u16*)(ws + (6u << 20));              // 2 MB
    u16*   Ob  = (u16*)(ws + (8u << 20));              // 2 MB  (2,4096,128) bf16
    u16*   Wc  = (u16*)(ws + (10u << 20));             // 16 KB (64,128) bf16
    float* bc  = (float*)(ws + (10u << 20) + 16384);   // 256 B f32
    u16*   Wcp_b = (u16*)(ws + (10u << 20) + 32768);   // 16 KB
    u16*   Wq_b  = (u16*)(ws + (10u << 20) + 49152);   // 32 KB
    u16*   Wk_b  = (u16*)(ws + (10u << 20) + 81920);   // 32 KB
    u16*   Wv_b  = (u16*)(ws + (10u << 20) + 114688);  // 32 KB
    float* out = (float*)d_out;

    hipLaunchKernelGGL(k_prep, dim3(257), dim3(256), 0, stream,
                       Wo, bo, Wout, bout, Wcp, Wq, Wk, Wv,
                       Wc, bc, Wcp_b, Wq_b, Wk_b, Wv_b);
    hipLaunchKernelGGL(k_embed, dim3(128), dim3(256), 0, stream, x, Wcp_b, bcp, pos, xf);
    hipLaunchKernelGGL(k_qkv, dim3(384), dim3(256), 0, stream, xf, Wq_b, Wk_b, Wv_b, Qb, Kb, Vb);
    hipLaunchKernelGGL(k_attn, dim3(256), dim3(256), 0, stream, Qb, Kb, Vb, Ob);
    hipLaunchKernelGGL(k_out, dim3(128), dim3(256), 0, stream, Ob, Wc, bc, x, gate, out);
}

// Round 4
// 122.084 us; speedup vs baseline: 1.6861x; 1.6861x over previous
//
#include <hip/hip_runtime.h>
#include <hip/hip_bf16.h>
#include <cstdint>

typedef unsigned short u16;
typedef __attribute__((ext_vector_type(8))) short short8;
typedef __attribute__((ext_vector_type(8))) float f32x8;
typedef __attribute__((ext_vector_type(4))) float f32x4;

#define MFMA(a, b, c) __builtin_amdgcn_mfma_f32_16x16x32_bf16((a), (b), (c), 0, 0, 0)

// B=2, S=4096, E=128, NH=2, HD=64, CIN=64, COUT=64
#define SEQ 4096
#define KSPLIT 4

static __device__ __forceinline__ float b2f(u16 u) {
    union { float f; uint32_t i; } c; c.i = ((uint32_t)u) << 16; return c.f;
}
static __device__ __forceinline__ u16 f2b(float f) {
    union { float f; uint32_t i; } c; c.f = f;
    uint32_t r = c.i + 0x7FFF + ((c.i >> 16) & 1);   // RNE f32->bf16
    return (u16)(r >> 16);
}
static __device__ __forceinline__ short8 ld8(const u16* p) {
    return *reinterpret_cast<const short8*>(p);
}
// async global->LDS: per-lane global src, wave-uniform LDS base + lane*16B
static __device__ __forceinline__ void gld16(const u16* g, u16* l) {
    __builtin_amdgcn_global_load_lds(
        (const __attribute__((address_space(1))) unsigned int*)g,
        (__attribute__((address_space(3))) unsigned int*)l, 16, 0, 0);
}

// ---- K0: Wc = Wout @ Wo (bf16), bc = bo @ Wout^T + bout (f32); weights f32->bf16 ----
__global__ void k_prep(const float* __restrict__ Wo, const float* __restrict__ bo,
                       const float* __restrict__ Wout, const float* __restrict__ bout,
                       const float* __restrict__ Wcp, const float* __restrict__ Wq,
                       const float* __restrict__ Wk, const float* __restrict__ Wv,
                       u16* __restrict__ Wc, float* __restrict__ bc,
                       u16* __restrict__ Wcp_b, u16* __restrict__ Wq_b,
                       u16* __restrict__ Wk_b, u16* __restrict__ Wv_b) {
    int idx = blockIdx.x * 256 + threadIdx.x;
    if (idx < 8192) {
        int co = idx >> 7, e = idx & 127;
        float s = 0.f;
        for (int k = 0; k < 128; k++)
            s += Wout[co * 128 + k] * Wo[k * 128 + e];
        Wc[idx] = f2b(s);
    } else if (idx < 8256) {
        int co = idx - 8192;
        float s = bout[co];
        for (int k = 0; k < 128; k++)
            s += bo[k] * Wout[co * 128 + k];
        bc[co] = s;
    } else if (idx < 16448) {
        int i = idx - 8256;  Wcp_b[i] = f2b(Wcp[i]);
    } else if (idx < 32832) {
        int i = idx - 16448; Wq_b[i] = f2b(Wq[i]);
    } else if (idx < 49216) {
        int i = idx - 32832; Wk_b[i] = f2b(Wk[i]);
    } else if (idx < 65600) {
        int i = idx - 49216; Wv_b[i] = f2b(Wv[i]);
    }
}

// ---- K1: xf = transpose(x) @ Wcp^T + bcp + pos ----
__global__ __launch_bounds__(256) void k_embed(const float* __restrict__ x,
                                               const u16* __restrict__ Wcp,
                                               const float* __restrict__ bcp,
                                               const float* __restrict__ pos,
                                               u16* __restrict__ xf) {
    __shared__ __align__(16) u16 xT[64][72];
    int blk = blockIdx.x;
    int b = blk >> 6, sb = (blk & 63) * 64;
    int t = threadIdx.x, w = t >> 6, l = t & 63, lc = l & 15, lg = l >> 4;

    const float* src = x + ((size_t)b * 64 + l) * SEQ + sb + w * 16;
    f32x8 a0 = *reinterpret_cast<const f32x8*>(src);
    f32x8 a1 = *reinterpret_cast<const f32x8*>(src + 8);
#pragma unroll
    for (int j = 0; j < 8; j++) {
        xT[w * 16 + j][l] = f2b(a0[j]);
        xT[w * 16 + 8 + j][l] = f2b(a1[j]);
    }
    __syncthreads();

    short8 af[2];
    af[0] = ld8(&xT[w * 16 + lc][lg * 8]);
    af[1] = ld8(&xT[w * 16 + lc][32 + lg * 8]);

#pragma unroll
    for (int nt = 0; nt < 8; nt++) {
        f32x4 acc = {0.f, 0.f, 0.f, 0.f};
#pragma unroll
        for (int ks = 0; ks < 2; ks++) {
            short8 bfr = ld8(Wcp + (nt * 16 + lc) * 64 + ks * 32 + lg * 8);
            acc = MFMA(af[ks], bfr, acc);
        }
        int e = nt * 16 + lc;
        float be = bcp[e];
#pragma unroll
        for (int r = 0; r < 4; r++) {
            int sr = sb + w * 16 + lg * 4 + r;
            float v = acc[r] + be + pos[(size_t)sr * 128 + e];
            xf[((size_t)b * SEQ + sr) * 128 + e] = f2b(v);
        }
    }
}

// ---- K2: Q/K = xf @ W^T (Q pre-scaled by 0.125*log2e); V stored TRANSPOSED (b,h,d,s) ----
__global__ __launch_bounds__(256) void k_qkv(const u16* __restrict__ xf,
                                             const u16* __restrict__ Wq,
                                             const u16* __restrict__ Wk,
                                             const u16* __restrict__ Wv,
                                             u16* __restrict__ Q, u16* __restrict__ K,
                                             u16* __restrict__ V) {
    int blk = blockIdx.x;
    int which = blk / 128, rb = blk % 128;
    const u16* W = (which == 0) ? Wq : (which == 1) ? Wk : Wv;
    u16* dst = (which == 0) ? Q : (which == 1) ? K : V;
    float scl = (which == 0) ? 0.18033688011112042f : 1.0f;  // 0.125*log2(e) for Q
    int b = rb >> 6, sb = (rb & 63) * 64;
    int t = threadIdx.x, w = t >> 6, l = t & 63, lc = l & 15, lg = l >> 4;

    short8 af[4];
#pragma unroll
    for (int ks = 0; ks < 4; ks++)
        af[ks] = ld8(xf + ((size_t)b * SEQ + sb + w * 16 + lc) * 128 + ks * 32 + lg * 8);

#pragma unroll
    for (int nt = 0; nt < 8; nt++) {
        f32x4 acc = {0.f, 0.f, 0.f, 0.f};
        if (which == 2) {
            // V^T = Wv @ xf^T : A=Wv rows (d), B=xf^T cols (s) -> coalesced V^T stores
#pragma unroll
            for (int ks = 0; ks < 4; ks++) {
                short8 bfr = ld8(W + (nt * 16 + lc) * 128 + ks * 32 + lg * 8);
                acc = MFMA(bfr, af[ks], acc);
            }
#pragma unroll
            for (int r = 0; r < 4; r++) {
                int d = nt * 16 + lg * 4 + r, h = d >> 6, dd = d & 63;
                dst[((size_t)(b * 2 + h) * 64 + dd) * SEQ + sb + w * 16 + lc] = f2b(acc[r]);
            }
        } else {
#pragma unroll
            for (int ks = 0; ks < 4; ks++) {
                short8 bfr = ld8(W + (nt * 16 + lc) * 128 + ks * 32 + lg * 8);
                acc = MFMA(af[ks], bfr, acc);
            }
            int e = nt * 16 + lc, h = e >> 6, d = e & 63;
#pragma unroll
            for (int r = 0; r < 4; r++) {
                int sr = sb + w * 16 + lg * 4 + r;
                dst[(((size_t)b * 2 + h) * SEQ + sr) * 64 + d] = f2b(acc[r] * scl);
            }
        }
    }
}

// ---- K3: flash attention, split-K. Block = (split, bh, qb64). 4 waves x 16 q-rows.
//  K/V 64-key tiles staged via global_load_lds with pre-swizzled global source
//  (chunk c at slot c^(row&7)) -> conflict-free b128 fragment reads. Double-buffered.
//  Unnormalized O (bf16) + (m,l) per row to ws; k_comb merges. ----
__global__ __launch_bounds__(256) void k_attn(const u16* __restrict__ Q,
                                              const u16* __restrict__ K,
                                              const u16* __restrict__ Vg,
                                              u16* __restrict__ Op,
                                              float2* __restrict__ ml) {
    __shared__ __align__(16) u16 Klds[2][4096];   // [key 64][d 64] swizzled
    __shared__ __align__(16) u16 Vlds[2][4096];   // [d 64][key 64] swizzled
    __shared__ __align__(16) u16 Pl[4][16][64];   // per-wave P [q][key] swizzled
    int blk = blockIdx.x;
    int split = blk >> 8, bh = (blk >> 6) & 3, qb = (blk & 63) * 64;
    int kbase = split * (SEQ / KSPLIT);
    const u16* Qp = Q + (size_t)bh * SEQ * 64;
    const u16* Kp = K + (size_t)bh * SEQ * 64;
    const u16* Vp = Vg + (size_t)bh * SEQ * 64;   // (d, s)
    int t = threadIdx.x, w = t >> 6, l = t & 63, lc = l & 15, lg = l >> 4;

    // staging: wave w covers K rows w*16..w*16+15 (two 8-row halves); chunk = l&7
    int swz8 = ((l & 7) ^ ((l >> 3) & 7)) * 8;
    const u16* kSrc = Kp + (size_t)(kbase + w * 16 + (l >> 3)) * 64 + swz8;
    const u16* vSrc = Vp + (size_t)(w * 16 + (l >> 3)) * SEQ + kbase + swz8;

    short8 qa[2];
    qa[0] = ld8(Qp + (size_t)(qb + w * 16 + lc) * 64 + lg * 8);
    qa[1] = ld8(Qp + (size_t)(qb + w * 16 + lc) * 64 + 32 + lg * 8);

    f32x4 oacc[4];
    float m[4], ls[4];
#pragma unroll
    for (int i = 0; i < 4; i++) {
        oacc[i] = (f32x4){0.f, 0.f, 0.f, 0.f};
        m[i] = -INFINITY;
        ls[i] = 0.f;
    }

    int c0 = (lg ^ (lc & 7)) * 8;  // swizzled chunk offset for ks=0 frag reads

    // wave w's tile region: u16 offset w*1024 (16 rows x 64); halves at +0 / +512
#define STAGE(buf, tt) do {                                           \
        const u16* ks_ = kSrc + (size_t)(tt) * 4096;                  \
        const u16* vs_ = vSrc + (tt) * 64;                            \
        gld16(ks_,           &Klds[buf][w * 1024]);                   \
        gld16(ks_ + 512,     &Klds[buf][w * 1024 + 512]);             \
        gld16(vs_,           &Vlds[buf][w * 1024]);                   \
        gld16(vs_ + 8 * SEQ, &Vlds[buf][w * 1024 + 512]);             \
    } while (0)

    STAGE(0, 0);
    __syncthreads();

    for (int tt = 0; tt < SEQ / KSPLIT / 64; tt++) {
        int cur = tt & 1;
        if (tt + 1 < SEQ / KSPLIT / 64) STAGE(cur ^ 1, tt + 1);

        const u16* kb = Klds[cur];
        const u16* vb = Vlds[cur];

        // scores S = Q K^T (Q pre-scaled, log2 domain)
        f32x4 sc[4];
#pragma unroll
        for (int nt = 0; nt < 4; nt++) {
            sc[nt] = (f32x4){0.f, 0.f, 0.f, 0.f};
            short8 kf0 = ld8(kb + (nt * 16 + lc) * 64 + c0);
            short8 kf1 = ld8(kb + (nt * 16 + lc) * 64 + (c0 ^ 32));
            sc[nt] = MFMA(qa[0], kf0, sc[nt]);
            sc[nt] = MFMA(qa[1], kf1, sc[nt]);
        }

        // online softmax (row = lg*4+r, cols over 16 lanes x 4 nt)
#pragma unroll
        for (int r = 0; r < 4; r++) {
            float mx = fmaxf(fmaxf(sc[0][r], sc[1][r]), fmaxf(sc[2][r], sc[3][r]));
            mx = fmaxf(mx, __shfl_xor(mx, 1));
            mx = fmaxf(mx, __shfl_xor(mx, 2));
            mx = fmaxf(mx, __shfl_xor(mx, 4));
            mx = fmaxf(mx, __shfl_xor(mx, 8));
            float mn = fmaxf(m[r], mx);
            float corr = exp2f(m[r] - mn);
            int qrow = lg * 4 + r;
            float rs = 0.f;
#pragma unroll
            for (int nt = 0; nt < 4; nt++) {
                float p = exp2f(sc[nt][r] - mn);
                rs += p;
                Pl[w][qrow][(((nt * 2 + (lc >> 3)) ^ (qrow & 7)) << 3) + (lc & 7)] = f2b(p);
            }
            rs += __shfl_xor(rs, 1);
            rs += __shfl_xor(rs, 2);
            rs += __shfl_xor(rs, 4);
            rs += __shfl_xor(rs, 8);
            ls[r] = ls[r] * corr + rs;
            m[r] = mn;
#pragma unroll
            for (int nt = 0; nt < 4; nt++) oacc[nt][r] *= corr;
        }

        // O += P @ V  (A = P from swizzled per-wave LDS, B = V^T frags)
#pragma unroll
        for (int ks = 0; ks < 2; ks++) {
            short8 pa = ld8(&Pl[w][lc][(((ks * 4 + lg) ^ (lc & 7)) << 3)]);
#pragma unroll
            for (int dt = 0; dt < 4; dt++) {
                short8 vf = ld8(vb + (dt * 16 + lc) * 64 + (ks ? (c0 ^ 32) : c0));
                oacc[dt] = MFMA(pa, vf, oacc[dt]);
            }
        }
        __syncthreads();
    }
#undef STAGE

    // epilogue: unnormalized bf16 partials
    size_t rowbase = (size_t)(split * 4 + bh) * SEQ + qb + w * 16;
#pragma unroll
    for (int dt = 0; dt < 4; dt++)
#pragma unroll
        for (int r = 0; r < 4; r++)
            Op[(rowbase + lg * 4 + r) * 64 + dt * 16 + lc] = f2b(oacc[dt][r]);
    if (lc == 0) {
#pragma unroll
        for (int r = 0; r < 4; r++) {
            float2 v; v.x = m[r]; v.y = ls[r];
            ml[rowbase + lg * 4 + r] = v;
        }
    }
}

// ---- K3b: merge KSPLIT partials -> O (B, S, 128) bf16 ----
__global__ __launch_bounds__(256) void k_comb(const u16* __restrict__ Op,
                                              const float2* __restrict__ ml,
                                              u16* __restrict__ O) {
    int tid = blockIdx.x * 256 + threadIdx.x;   // 65536 = 16384 rows x 4 d-quads
    int row = tid >> 2, dq = tid & 3;
    float2 e0 = ml[row], e1 = ml[16384 + row], e2 = ml[32768 + row], e3 = ml[49152 + row];
    float ms = fmaxf(fmaxf(e0.x, e1.x), fmaxf(e2.x, e3.x));
    float c0 = exp2f(e0.x - ms), c1 = exp2f(e1.x - ms);
    float c2 = exp2f(e2.x - ms), c3 = exp2f(e3.x - ms);
    float inv = 1.0f / (c0 * e0.y + c1 * e1.y + c2 * e2.y + c3 * e3.y);

    const u16* p0 = Op + ((size_t)row) * 64 + dq * 16;
    const u16* p1 = Op + ((size_t)(16384 + row)) * 64 + dq * 16;
    const u16* p2 = Op + ((size_t)(32768 + row)) * 64 + dq * 16;
    const u16* p3 = Op + ((size_t)(49152 + row)) * 64 + dq * 16;

    int bh = row >> 12, s = row & 4095, b = bh >> 1, h = bh & 1;
    u16* dst = O + ((size_t)b * SEQ + s) * 128 + h * 64 + dq * 16;
    short8 out[2];
#pragma unroll
    for (int half = 0; half < 2; half++) {
        short8 a0 = ld8(p0 + half * 8), a1 = ld8(p1 + half * 8);
        short8 a2 = ld8(p2 + half * 8), a3 = ld8(p3 + half * 8);
#pragma unroll
        for (int e = 0; e < 8; e++) {
            float acc = c0 * b2f((u16)a0[e]) + c1 * b2f((u16)a1[e]) +
                        c2 * b2f((u16)a2[e]) + c3 * b2f((u16)a3[e]);
            out[half][e] = (short)f2b(acc * inv);
        }
    }
    *reinterpret_cast<short8*>(dst) = out[0];
    *reinterpret_cast<short8*>(dst + 8) = out[1];
}

// ---- K4: out[b][co][s] = O[b][s][:] . Wc[co][:] + bc[co] + gate*x[b][co][s] ----
__global__ __launch_bounds__(256) void k_out(const u16* __restrict__ O,
                                             const u16* __restrict__ Wc,
                                             const float* __restrict__ bc,
                                             const float* __restrict__ x,
                                             const float* __restrict__ gate,
                                             float* __restrict__ out) {
    int blk = blockIdx.x;
    int b = blk >> 6, sb = (blk & 63) * 64;
    int t = threadIdx.x, w = t >> 6, l = t & 63, lc = l & 15, lg = l >> 4;
    float g = gate[0];

    short8 af[4];
#pragma unroll
    for (int ks = 0; ks < 4; ks++)
        af[ks] = ld8(Wc + (w * 16 + lc) * 128 + ks * 32 + lg * 8);

#pragma unroll
    for (int st = 0; st < 4; st++) {
        f32x4 acc = {0.f, 0.f, 0.f, 0.f};
#pragma unroll
        for (int ks = 0; ks < 4; ks++) {
            short8 bfr = ld8(O + ((size_t)b * SEQ + sb + st * 16 + lc) * 128 + ks * 32 + lg * 8);
            acc = MFMA(af[ks], bfr, acc);
        }
#pragma unroll
        for (int r = 0; r < 4; r++) {
            int co = w * 16 + lg * 4 + r;
            int s = sb + st * 16 + lc;
            size_t idx = ((size_t)b * 64 + co) * SEQ + s;
            out[idx] = acc[r] + bc[co] + g * x[idx];
        }
    }
}

extern "C" void kernel_launch(void* const* d_in, const int* in_sizes, int n_in,
                              void* d_out, int out_size, void* d_ws, size_t ws_size,
                              hipStream_t stream) {
    const float* x    = (const float*)d_in[0];
    const float* Wcp  = (const float*)d_in[1];
    const float* bcp  = (const float*)d_in[2];
    const float* Wq   = (const float*)d_in[3];
    const float* Wk   = (const float*)d_in[4];
    const float* Wv   = (const float*)d_in[5];
    const float* Wo   = (const float*)d_in[6];
    const float* bo   = (const float*)d_in[7];
    const float* Wout = (const float*)d_in[8];
    const float* bout = (const float*)d_in[9];
    const float* pos  = (const float*)d_in[10];
    const float* gate = (const float*)d_in[11];

    char* ws = (char*)d_ws;
    // layout (peak 18.5 MB):
    u16*    xf   = (u16*)(ws);                           // [0,2MB) bf16, dead after k_qkv
    float2* mlp  = (float2*)(ws);                        // [0,512KB) overlaps dead xf
    u16*    Qb   = (u16*)(ws + (2u << 20));              // [2,4) MB
    u16*    Kb   = (u16*)(ws + (4u << 20));              // [4,6) MB
    u16*    Vt   = (u16*)(ws + (6u << 20));              // [6,8) MB  (b,h,d,s)
    u16*    Ob   = (u16*)(ws + (8u << 20));              // [8,10) MB
    u16*    Wc   = (u16*)(ws + (10u << 20));             // 16 KB
    float*  bc   = (float*)(ws + (10u << 20) + 16384);   // 256 B
    u16*    Wcp_b = (u16*)(ws + (10u << 20) + 32768);    // 16 KB
    u16*    Wq_b  = (u16*)(ws + (10u << 20) + 49152);    // 32 KB
    u16*    Wk_b  = (u16*)(ws + (10u << 20) + 81920);    // 32 KB
    u16*    Wv_b  = (u16*)(ws + (10u << 20) + 114688);   // 32 KB
    u16*    Opb  = (u16*)(ws + (10u << 20) + (512u << 10)); // [10.5,18.5) MB bf16 partials
    float* out = (float*)d_out;

    hipLaunchKernelGGL(k_prep, dim3(257), dim3(256), 0, stream,
                       Wo, bo, Wout, bout, Wcp, Wq, Wk, Wv,
                       Wc, bc, Wcp_b, Wq_b, Wk_b, Wv_b);
    hipLaunchKernelGGL(k_embed, dim3(128), dim3(256), 0, stream, x, Wcp_b, bcp, pos, xf);
    hipLaunchKernelGGL(k_qkv, dim3(384), dim3(256), 0, stream, xf, Wq_b, Wk_b, Wv_b, Qb, Kb, Vt);
    hipLaunchKernelGGL(k_attn, dim3(256 * KSPLIT), dim3(256), 0, stream, Qb, Kb, Vt, Opb, mlp);
    hipLaunchKernelGGL(k_comb, dim3(256), dim3(256), 0, stream, Opb, mlp, Ob);
    hipLaunchKernelGGL(k_out, dim3(128), dim3(256), 0, stream, Ob, Wc, bc, x, gate, out);
}

// Round 5
// 85.087 us; speedup vs baseline: 2.4192x; 1.4348x over previous
//
#include <hip/hip_runtime.h>
#include <hip/hip_bf16.h>
#include <cstdint>

typedef unsigned short u16;
typedef __attribute__((ext_vector_type(8))) short short8;
typedef __attribute__((ext_vector_type(8))) float f32x8;
typedef __attribute__((ext_vector_type(4))) float f32x4;

#define MFMA(a, b, c) __builtin_amdgcn_mfma_f32_16x16x32_bf16((a), (b), (c), 0, 0, 0)

// B=2, S=4096, E=128, NH=2, HD=64, CIN=64, COUT=64
#define SEQ 4096
#define KSPLIT 4

static __device__ __forceinline__ float b2f(u16 u) {
    union { float f; uint32_t i; } c; c.i = ((uint32_t)u) << 16; return c.f;
}
static __device__ __forceinline__ u16 f2b(float f) {
    union { float f; uint32_t i; } c; c.f = f;
    uint32_t r = c.i + 0x7FFF + ((c.i >> 16) & 1);   // RNE f32->bf16
    return (u16)(r >> 16);
}
static __device__ __forceinline__ short8 ld8(const u16* p) {
    return *reinterpret_cast<const short8*>(p);
}
// pack two f32 -> bf16x2 word (lo = a, hi = b), RNE
static __device__ __forceinline__ uint32_t pk2(float a, float b) {
    uint32_t r;
    asm("v_cvt_pk_bf16_f32 %0, %1, %2" : "=v"(r) : "v"(a), "v"(b));
    return r;
}
// async global->LDS: per-lane global src, wave-uniform LDS base + lane*16B
static __device__ __forceinline__ void gld16(const u16* g, u16* l) {
    __builtin_amdgcn_global_load_lds(
        (const __attribute__((address_space(1))) unsigned int*)g,
        (__attribute__((address_space(3))) unsigned int*)l, 16, 0, 0);
}

// ---- K0: Wc = Wout @ Wo (bf16), bc = bo @ Wout^T + bout (f32); weights f32->bf16 ----
__global__ void k_prep(const float* __restrict__ Wo, const float* __restrict__ bo,
                       const float* __restrict__ Wout, const float* __restrict__ bout,
                       const float* __restrict__ Wcp, const float* __restrict__ Wq,
                       const float* __restrict__ Wk, const float* __restrict__ Wv,
                       u16* __restrict__ Wc, float* __restrict__ bc,
                       u16* __restrict__ Wcp_b, u16* __restrict__ Wq_b,
                       u16* __restrict__ Wk_b, u16* __restrict__ Wv_b) {
    int idx = blockIdx.x * 256 + threadIdx.x;
    if (idx < 8192) {
        int co = idx >> 7, e = idx & 127;
        float s = 0.f;
        for (int k = 0; k < 128; k++)
            s += Wout[co * 128 + k] * Wo[k * 128 + e];
        Wc[idx] = f2b(s);
    } else if (idx < 8256) {
        int co = idx - 8192;
        float s = bout[co];
        for (int k = 0; k < 128; k++)
            s += bo[k] * Wout[co * 128 + k];
        bc[co] = s;
    } else if (idx < 16448) {
        int i = idx - 8256;  Wcp_b[i] = f2b(Wcp[i]);
    } else if (idx < 32832) {
        int i = idx - 16448; Wq_b[i] = f2b(Wq[i]);
    } else if (idx < 49216) {
        int i = idx - 32832; Wk_b[i] = f2b(Wk[i]);
    } else if (idx < 65600) {
        int i = idx - 49216; Wv_b[i] = f2b(Wv[i]);
    }
}

// ---- K1: xf = transpose(x) @ Wcp^T + bcp + pos ----
__global__ __launch_bounds__(256) void k_embed(const float* __restrict__ x,
                                               const u16* __restrict__ Wcp,
                                               const float* __restrict__ bcp,
                                               const float* __restrict__ pos,
                                               u16* __restrict__ xf) {
    __shared__ __align__(16) u16 xT[64][72];
    int blk = blockIdx.x;
    int b = blk >> 6, sb = (blk & 63) * 64;
    int t = threadIdx.x, w = t >> 6, l = t & 63, lc = l & 15, lg = l >> 4;

    const float* src = x + ((size_t)b * 64 + l) * SEQ + sb + w * 16;
    f32x8 a0 = *reinterpret_cast<const f32x8*>(src);
    f32x8 a1 = *reinterpret_cast<const f32x8*>(src + 8);
#pragma unroll
    for (int j = 0; j < 8; j++) {
        xT[w * 16 + j][l] = f2b(a0[j]);
        xT[w * 16 + 8 + j][l] = f2b(a1[j]);
    }
    __syncthreads();

    short8 af[2];
    af[0] = ld8(&xT[w * 16 + lc][lg * 8]);
    af[1] = ld8(&xT[w * 16 + lc][32 + lg * 8]);

#pragma unroll
    for (int nt = 0; nt < 8; nt++) {
        f32x4 acc = {0.f, 0.f, 0.f, 0.f};
#pragma unroll
        for (int ks = 0; ks < 2; ks++) {
            short8 bfr = ld8(Wcp + (nt * 16 + lc) * 64 + ks * 32 + lg * 8);
            acc = MFMA(af[ks], bfr, acc);
        }
        int e = nt * 16 + lc;
        float be = bcp[e];
#pragma unroll
        for (int r = 0; r < 4; r++) {
            int sr = sb + w * 16 + lg * 4 + r;
            float v = acc[r] + be + pos[(size_t)sr * 128 + e];
            xf[((size_t)b * SEQ + sr) * 128 + e] = f2b(v);
        }
    }
}

// ---- K2: Q/K = xf @ W^T (Q pre-scaled by 0.125*log2e); V stored TRANSPOSED (b,h,d,s) ----
__global__ __launch_bounds__(256) void k_qkv(const u16* __restrict__ xf,
                                             const u16* __restrict__ Wq,
                                             const u16* __restrict__ Wk,
                                             const u16* __restrict__ Wv,
                                             u16* __restrict__ Q, u16* __restrict__ K,
                                             u16* __restrict__ V) {
    int blk = blockIdx.x;
    int which = blk / 128, rb = blk % 128;
    const u16* W = (which == 0) ? Wq : (which == 1) ? Wk : Wv;
    u16* dst = (which == 0) ? Q : (which == 1) ? K : V;
    float scl = (which == 0) ? 0.18033688011112042f : 1.0f;  // 0.125*log2(e) for Q
    int b = rb >> 6, sb = (rb & 63) * 64;
    int t = threadIdx.x, w = t >> 6, l = t & 63, lc = l & 15, lg = l >> 4;

    short8 af[4];
#pragma unroll
    for (int ks = 0; ks < 4; ks++)
        af[ks] = ld8(xf + ((size_t)b * SEQ + sb + w * 16 + lc) * 128 + ks * 32 + lg * 8);

#pragma unroll
    for (int nt = 0; nt < 8; nt++) {
        f32x4 acc = {0.f, 0.f, 0.f, 0.f};
        if (which == 2) {
            // V^T = Wv @ xf^T : A=Wv rows (d), B=xf^T cols (s) -> coalesced V^T stores
#pragma unroll
            for (int ks = 0; ks < 4; ks++) {
                short8 bfr = ld8(W + (nt * 16 + lc) * 128 + ks * 32 + lg * 8);
                acc = MFMA(bfr, af[ks], acc);
            }
#pragma unroll
            for (int r = 0; r < 4; r++) {
                int d = nt * 16 + lg * 4 + r, h = d >> 6, dd = d & 63;
                dst[((size_t)(b * 2 + h) * 64 + dd) * SEQ + sb + w * 16 + lc] = f2b(acc[r]);
            }
        } else {
#pragma unroll
            for (int ks = 0; ks < 4; ks++) {
                short8 bfr = ld8(W + (nt * 16 + lc) * 128 + ks * 32 + lg * 8);
                acc = MFMA(af[ks], bfr, acc);
            }
            int e = nt * 16 + lc, h = e >> 6, d = e & 63;
#pragma unroll
            for (int r = 0; r < 4; r++) {
                int sr = sb + w * 16 + lg * 4 + r;
                dst[(((size_t)b * 2 + h) * SEQ + sr) * 64 + d] = f2b(acc[r] * scl);
            }
        }
    }
}

// ---- K3: flash attention, split-K, SWAPPED QK^T (scores lane-local per q-row).
//  sc = MFMA(K_frag, Q_frag): lane holds 16 scores for q = lane&15.
//  In-lane max/sum trees + 2 shfl_xor; defer-max (THR=8, log2); P packed via
//  v_cvt_pk_bf16_f32 into swizzled per-wave LDS. K/V staged via global_load_lds
//  with pre-swizzled source, double-buffered. Unnormalized bf16 partials + (m,l). ----
__global__ __launch_bounds__(256) void k_attn(const u16* __restrict__ Q,
                                              const u16* __restrict__ K,
                                              const u16* __restrict__ Vg,
                                              u16* __restrict__ Op,
                                              float2* __restrict__ ml) {
    __shared__ __align__(16) u16 Klds[2][4096];   // [key 64][d 64] swizzled
    __shared__ __align__(16) u16 Vlds[2][4096];   // [d 64][key 64] swizzled
    __shared__ __align__(16) u16 Pl[4][16][64];   // per-wave P [q 16][key 64] swizzled
    int blk = blockIdx.x;
    int split = blk >> 8, bh = (blk >> 6) & 3, qb = (blk & 63) * 64;
    int kbase = split * (SEQ / KSPLIT);
    const u16* Qp = Q + (size_t)bh * SEQ * 64;
    const u16* Kp = K + (size_t)bh * SEQ * 64;
    const u16* Vp = Vg + (size_t)bh * SEQ * 64;   // (d, s)
    int t = threadIdx.x, w = t >> 6, l = t & 63, lc = l & 15, lg = l >> 4;
    uint32_t* plw = (uint32_t*)&Pl[w][0][0];      // row stride 32 u32

    // staging: wave w covers K rows w*16..w*16+15 (two 8-row halves); chunk = l&7
    int swz8 = ((l & 7) ^ ((l >> 3) & 7)) * 8;
    const u16* kSrc = Kp + (size_t)(kbase + w * 16 + (l >> 3)) * 64 + swz8;
    const u16* vSrc = Vp + (size_t)(w * 16 + (l >> 3)) * SEQ + kbase + swz8;

    short8 qa[2];
    qa[0] = ld8(Qp + (size_t)(qb + w * 16 + lc) * 64 + lg * 8);
    qa[1] = ld8(Qp + (size_t)(qb + w * 16 + lc) * 64 + 32 + lg * 8);

    f32x4 oacc[4];
#pragma unroll
    for (int i = 0; i < 4; i++) oacc[i] = (f32x4){0.f, 0.f, 0.f, 0.f};
    float m = -INFINITY, ls = 0.f;

    int c0 = (lg ^ (lc & 7)) * 8;  // swizzled chunk offset for frag reads

    // wave w's tile region: u16 offset w*1024 (16 rows x 64); halves at +0 / +512
#define STAGE(buf, tt) do {                                           \
        const u16* ks_ = kSrc + (size_t)(tt) * 4096;                  \
        const u16* vs_ = vSrc + (tt) * 64;                            \
        gld16(ks_,           &Klds[buf][w * 1024]);                   \
        gld16(ks_ + 512,     &Klds[buf][w * 1024 + 512]);             \
        gld16(vs_,           &Vlds[buf][w * 1024]);                   \
        gld16(vs_ + 8 * SEQ, &Vlds[buf][w * 1024 + 512]);             \
    } while (0)

    STAGE(0, 0);
    __syncthreads();

    for (int tt = 0; tt < SEQ / KSPLIT / 64; tt++) {
        int cur = tt & 1;
        if (tt + 1 < SEQ / KSPLIT / 64) STAGE(cur ^ 1, tt + 1);

        const u16* kb = Klds[cur];
        const u16* vb = Vlds[cur];

        // scores, SWAPPED: sc[nt][r] = S[key = nt*16 + lg*4 + r][q = lc]
        f32x4 sc[4];
#pragma unroll
        for (int nt = 0; nt < 4; nt++) {
            sc[nt] = (f32x4){0.f, 0.f, 0.f, 0.f};
            short8 kf0 = ld8(kb + (nt * 16 + lc) * 64 + c0);
            short8 kf1 = ld8(kb + (nt * 16 + lc) * 64 + (c0 ^ 32));
            sc[nt] = MFMA(kf0, qa[0], sc[nt]);
            sc[nt] = MFMA(kf1, qa[1], sc[nt]);
        }

        // row max: in-lane tree + 2 shfl (4 lanes share q)
        float mx = sc[0][0];
#pragma unroll
        for (int nt = 0; nt < 4; nt++)
#pragma unroll
            for (int r = 0; r < 4; r++) mx = fmaxf(mx, sc[nt][r]);
        mx = fmaxf(mx, __shfl_xor(mx, 16));
        mx = fmaxf(mx, __shfl_xor(mx, 32));

        // defer-max: rescale only when max grows > 8 (log2 units)
        if (__any(mx - m > 8.f)) {
            float mn = fmaxf(m, mx);
            float corr = exp2f(m - mn);
#pragma unroll
            for (int r = 0; r < 4; r++) {
                float cr = __shfl(corr, lg * 4 + r);
#pragma unroll
                for (int dt = 0; dt < 4; dt++) oacc[dt][r] *= cr;
            }
            ls *= corr;
            m = mn;
        }

        // exp + in-lane sum + pack P (bf16x2 words)
        float rs = 0.f;
        uint32_t pk[8];
#pragma unroll
        for (int nt = 0; nt < 4; nt++) {
            float p0 = exp2f(sc[nt][0] - m), p1 = exp2f(sc[nt][1] - m);
            float p2 = exp2f(sc[nt][2] - m), p3 = exp2f(sc[nt][3] - m);
            rs += (p0 + p1) + (p2 + p3);
            pk[nt * 2]     = pk2(p0, p1);
            pk[nt * 2 + 1] = pk2(p2, p3);
        }
        rs += __shfl_xor(rs, 16);
        rs += __shfl_xor(rs, 32);
        ls += rs;

        // store packed P: row q=lc, chunk (nt*2 + (lg>>1)) at chunk^(lc&7)
#pragma unroll
        for (int nt = 0; nt < 4; nt++) {
            int base = lc * 32 + (((nt * 2 + (lg >> 1)) ^ (lc & 7)) << 2) + (lg & 1) * 2;
            plw[base]     = pk[nt * 2];
            plw[base + 1] = pk[nt * 2 + 1];
        }

        // O += P @ V  (A = P from swizzled per-wave LDS, B = V^T frags)
#pragma unroll
        for (int ks = 0; ks < 2; ks++) {
            short8 pa = ld8(&Pl[w][lc][(((ks * 4 + lg) ^ (lc & 7)) << 3)]);
#pragma unroll
            for (int dt = 0; dt < 4; dt++) {
                short8 vf = ld8(vb + (dt * 16 + lc) * 64 + (ks ? (c0 ^ 32) : c0));
                oacc[dt] = MFMA(pa, vf, oacc[dt]);
            }
        }
        __syncthreads();
    }
#undef STAGE

    // epilogue: unnormalized bf16 partials + per-row (m, ls)
    size_t rowbase = (size_t)(split * 4 + bh) * SEQ + qb + w * 16;
#pragma unroll
    for (int dt = 0; dt < 4; dt++)
#pragma unroll
        for (int r = 0; r < 4; r++)
            Op[(rowbase + lg * 4 + r) * 64 + dt * 16 + lc] = f2b(oacc[dt][r]);
    if (l < 16) {
        float2 v; v.x = m; v.y = ls;
        ml[rowbase + lc] = v;
    }
}

// ---- K3b: merge KSPLIT partials -> O (B, S, 128) bf16 ----
__global__ __launch_bounds__(256) void k_comb(const u16* __restrict__ Op,
                                              const float2* __restrict__ ml,
                                              u16* __restrict__ O) {
    int tid = blockIdx.x * 256 + threadIdx.x;   // 65536 = 16384 rows x 4 d-quads
    int row = tid >> 2, dq = tid & 3;
    float2 e0 = ml[row], e1 = ml[16384 + row], e2 = ml[32768 + row], e3 = ml[49152 + row];
    float ms = fmaxf(fmaxf(e0.x, e1.x), fmaxf(e2.x, e3.x));
    float c0 = exp2f(e0.x - ms), c1 = exp2f(e1.x - ms);
    float c2 = exp2f(e2.x - ms), c3 = exp2f(e3.x - ms);
    float inv = 1.0f / (c0 * e0.y + c1 * e1.y + c2 * e2.y + c3 * e3.y);

    const u16* p0 = Op + ((size_t)row) * 64 + dq * 16;
    const u16* p1 = Op + ((size_t)(16384 + row)) * 64 + dq * 16;
    const u16* p2 = Op + ((size_t)(32768 + row)) * 64 + dq * 16;
    const u16* p3 = Op + ((size_t)(49152 + row)) * 64 + dq * 16;

    int bh = row >> 12, s = row & 4095, b = bh >> 1, h = bh & 1;
    u16* dst = O + ((size_t)b * SEQ + s) * 128 + h * 64 + dq * 16;
    short8 out[2];
#pragma unroll
    for (int half = 0; half < 2; half++) {
        short8 a0 = ld8(p0 + half * 8), a1 = ld8(p1 + half * 8);
        short8 a2 = ld8(p2 + half * 8), a3 = ld8(p3 + half * 8);
#pragma unroll
        for (int e = 0; e < 8; e++) {
            float acc = c0 * b2f((u16)a0[e]) + c1 * b2f((u16)a1[e]) +
                        c2 * b2f((u16)a2[e]) + c3 * b2f((u16)a3[e]);
            out[half][e] = (short)f2b(acc * inv);
        }
    }
    *reinterpret_cast<short8*>(dst) = out[0];
    *reinterpret_cast<short8*>(dst + 8) = out[1];
}

// ---- K4: out[b][co][s] = O[b][s][:] . Wc[co][:] + bc[co] + gate*x[b][co][s] ----
__global__ __launch_bounds__(256) void k_out(const u16* __restrict__ O,
                                             const u16* __restrict__ Wc,
                                             const float* __restrict__ bc,
                                             const float* __restrict__ x,
                                             const float* __restrict__ gate,
                                             float* __restrict__ out) {
    int blk = blockIdx.x;
    int b = blk >> 6, sb = (blk & 63) * 64;
    int t = threadIdx.x, w = t >> 6, l = t & 63, lc = l & 15, lg = l >> 4;
    float g = gate[0];

    short8 af[4];
#pragma unroll
    for (int ks = 0; ks < 4; ks++)
        af[ks] = ld8(Wc + (w * 16 + lc) * 128 + ks * 32 + lg * 8);

#pragma unroll
    for (int st = 0; st < 4; st++) {
        f32x4 acc = {0.f, 0.f, 0.f, 0.f};
#pragma unroll
        for (int ks = 0; ks < 4; ks++) {
            short8 bfr = ld8(O + ((size_t)b * SEQ + sb + st * 16 + lc) * 128 + ks * 32 + lg * 8);
            acc = MFMA(af[ks], bfr, acc);
        }
#pragma unroll
        for (int r = 0; r < 4; r++) {
            int co = w * 16 + lg * 4 + r;
            int s = sb + st * 16 + lc;
            size_t idx = ((size_t)b * 64 + co) * SEQ + s;
            out[idx] = acc[r] + bc[co] + g * x[idx];
        }
    }
}

extern "C" void kernel_launch(void* const* d_in, const int* in_sizes, int n_in,
                              void* d_out, int out_size, void* d_ws, size_t ws_size,
                              hipStream_t stream) {
    const float* x    = (const float*)d_in[0];
    const float* Wcp  = (const float*)d_in[1];
    const float* bcp  = (const float*)d_in[2];
    const float* Wq   = (const float*)d_in[3];
    const float* Wk   = (const float*)d_in[4];
    const float* Wv   = (const float*)d_in[5];
    const float* Wo   = (const float*)d_in[6];
    const float* bo   = (const float*)d_in[7];
    const float* Wout = (const float*)d_in[8];
    const float* bout = (const float*)d_in[9];
    const float* pos  = (const float*)d_in[10];
    const float* gate = (const float*)d_in[11];

    char* ws = (char*)d_ws;
    // layout (peak 18.5 MB):
    u16*    xf   = (u16*)(ws);                           // [0,2MB) bf16, dead after k_qkv
    float2* mlp  = (float2*)(ws);                        // [0,512KB) overlaps dead xf
    u16*    Qb   = (u16*)(ws + (2u << 20));              // [2,4) MB
    u16*    Kb   = (u16*)(ws + (4u << 20));              // [4,6) MB
    u16*    Vt   = (u16*)(ws + (6u << 20));              // [6,8) MB  (b,h,d,s)
    u16*    Ob   = (u16*)(ws + (8u << 20));              // [8,10) MB
    u16*    Wc   = (u16*)(ws + (10u << 20));             // 16 KB
    float*  bc   = (float*)(ws + (10u << 20) + 16384);   // 256 B
    u16*    Wcp_b = (u16*)(ws + (10u << 20) + 32768);    // 16 KB
    u16*    Wq_b  = (u16*)(ws + (10u << 20) + 49152);    // 32 KB
    u16*    Wk_b  = (u16*)(ws + (10u << 20) + 81920);    // 32 KB
    u16*    Wv_b  = (u16*)(ws + (10u << 20) + 114688);   // 32 KB
    u16*    Opb  = (u16*)(ws + (10u << 20) + (512u << 10)); // [10.5,18.5) MB bf16 partials
    float* out = (float*)d_out;

    hipLaunchKernelGGL(k_prep, dim3(257), dim3(256), 0, stream,
                       Wo, bo, Wout, bout, Wcp, Wq, Wk, Wv,
                       Wc, bc, Wcp_b, Wq_b, Wk_b, Wv_b);
    hipLaunchKernelGGL(k_embed, dim3(128), dim3(256), 0, stream, x, Wcp_b, bcp, pos, xf);
    hipLaunchKernelGGL(k_qkv, dim3(384), dim3(256), 0, stream, xf, Wq_b, Wk_b, Wv_b, Qb, Kb, Vt);
    hipLaunchKernelGGL(k_attn, dim3(256 * KSPLIT), dim3(256), 0, stream, Qb, Kb, Vt, Opb, mlp);
    hipLaunchKernelGGL(k_comb, dim3(256), dim3(256), 0, stream, Opb, mlp, Ob);
    hipLaunchKernelGGL(k_out, dim3(128), dim3(256), 0, stream, Ob, Wc, bc, x, gate, out);
}

// Round 6
// 66.623 us; speedup vs baseline: 3.0897x; 1.2771x over previous
//
#include <hip/hip_runtime.h>
#include <hip/hip_bf16.h>
#include <cstdint>

typedef unsigned short u16;
typedef __attribute__((ext_vector_type(8))) short short8;
typedef __attribute__((ext_vector_type(8))) float f32x8;
typedef __attribute__((ext_vector_type(4))) float f32x4;

#define MFMA(a, b, c) __builtin_amdgcn_mfma_f32_16x16x32_bf16((a), (b), (c), 0, 0, 0)

// B=2, S=4096, E=128, NH=2, HD=64, CIN=64, COUT=64
#define SEQ 4096
#define KSPLIT 4

static __device__ __forceinline__ float b2f(u16 u) {
    union { float f; uint32_t i; } c; c.i = ((uint32_t)u) << 16; return c.f;
}
static __device__ __forceinline__ u16 f2b(float f) {
    union { float f; uint32_t i; } c; c.f = f;
    uint32_t r = c.i + 0x7FFF + ((c.i >> 16) & 1);   // RNE f32->bf16
    return (u16)(r >> 16);
}
static __device__ __forceinline__ short8 ld8(const u16* p) {
    return *reinterpret_cast<const short8*>(p);
}
// pack two f32 -> bf16x2 word (lo = a, hi = b), RNE
static __device__ __forceinline__ uint32_t pk2(float a, float b) {
    uint32_t r;
    asm("v_cvt_pk_bf16_f32 %0, %1, %2" : "=v"(r) : "v"(a), "v"(b));
    return r;
}
// async global->LDS: per-lane global src, wave-uniform LDS base + lane*16B
static __device__ __forceinline__ void gld16(const u16* g, u16* l) {
    __builtin_amdgcn_global_load_lds(
        (const __attribute__((address_space(1))) unsigned int*)g,
        (__attribute__((address_space(3))) unsigned int*)l, 16, 0, 0);
}

// ---- K0: Wc = Wout @ Wo (bf16), bc = bo @ Wout^T + bout (f32); weights f32->bf16 ----
__global__ void k_prep(const float* __restrict__ Wo, const float* __restrict__ bo,
                       const float* __restrict__ Wout, const float* __restrict__ bout,
                       const float* __restrict__ Wcp, const float* __restrict__ Wq,
                       const float* __restrict__ Wk, const float* __restrict__ Wv,
                       u16* __restrict__ Wc, float* __restrict__ bc,
                       u16* __restrict__ Wcp_b, u16* __restrict__ Wq_b,
                       u16* __restrict__ Wk_b, u16* __restrict__ Wv_b) {
    int idx = blockIdx.x * 256 + threadIdx.x;
    if (idx < 8192) {
        int co = idx >> 7, e = idx & 127;
        float s = 0.f;
        for (int k = 0; k < 128; k++)
            s += Wout[co * 128 + k] * Wo[k * 128 + e];
        Wc[idx] = f2b(s);
    } else if (idx < 8256) {
        int co = idx - 8192;
        float s = bout[co];
        for (int k = 0; k < 128; k++)
            s += bo[k] * Wout[co * 128 + k];
        bc[co] = s;
    } else if (idx < 16448) {
        int i = idx - 8256;  Wcp_b[i] = f2b(Wcp[i]);
    } else if (idx < 32832) {
        int i = idx - 16448; Wq_b[i] = f2b(Wq[i]);
    } else if (idx < 49216) {
        int i = idx - 32832; Wk_b[i] = f2b(Wk[i]);
    } else if (idx < 65600) {
        int i = idx - 49216; Wv_b[i] = f2b(Wv[i]);
    }
}

// ---- K1: FUSED embed+qkv. Grid 256 = b*128 + sblk (32 s-rows each).
//  x^T tile -> xf (in swizzled LDS, never global) -> Q/K (b,h,s,d) + V^T (b,h,d,s). ----
__global__ __launch_bounds__(256) void k_front(const float* __restrict__ x,
                                               const u16* __restrict__ Wcp,
                                               const float* __restrict__ bcp,
                                               const float* __restrict__ pos,
                                               const u16* __restrict__ Wq,
                                               const u16* __restrict__ Wk,
                                               const u16* __restrict__ Wv,
                                               u16* __restrict__ Q, u16* __restrict__ K,
                                               u16* __restrict__ V) {
    __shared__ __align__(16) u16 xT[32][72];     // [s][c] transposed input
    __shared__ __align__(16) u16 xfl[32 * 128];  // xf tile, chunk-XOR swizzled
    int blk = blockIdx.x;
    int b = blk >> 7, sb = (blk & 127) * 32;
    int t = threadIdx.x, w = t >> 6, l = t & 63, lc = l & 15, lg = l >> 4;

    // stage x^T: thread t -> channel c = t&63, s-octet t>>6
    {
        int c = t & 63, so = t >> 6;
        const float* src = x + ((size_t)b * 64 + c) * SEQ + sb + so * 8;
        f32x8 a0 = *reinterpret_cast<const f32x8*>(src);
#pragma unroll
        for (int j = 0; j < 8; j++) xT[so * 8 + j][c] = f2b(a0[j]);
    }
    __syncthreads();

    // phase 1: xf = xT @ Wcp^T + bcp + pos  -> swizzled LDS
    {
        int rt = w >> 1, eh = w & 1;  // row-tile, e-half
        short8 af[2];
        af[0] = ld8(&xT[rt * 16 + lc][lg * 8]);
        af[1] = ld8(&xT[rt * 16 + lc][32 + lg * 8]);
#pragma unroll
        for (int et = 0; et < 4; et++) {
            int nt = eh * 4 + et;
            f32x4 acc = {0.f, 0.f, 0.f, 0.f};
#pragma unroll
            for (int ks = 0; ks < 2; ks++) {
                short8 bfr = ld8(Wcp + (nt * 16 + lc) * 64 + ks * 32 + lg * 8);
                acc = MFMA(af[ks], bfr, acc);
            }
            int e = nt * 16 + lc;
            float be = bcp[e];
            int chunk = e >> 3;
#pragma unroll
            for (int r = 0; r < 4; r++) {
                int sl = rt * 16 + lg * 4 + r;
                float v = acc[r] + be + pos[(size_t)(sb + sl) * 128 + e];
                xfl[sl * 128 + ((chunk ^ (sl & 7)) << 3) + (e & 7)] = f2b(v);
            }
        }
    }
    __syncthreads();

    // phase 2: Q/K/V from LDS xf
    {
        int st = w & 1, hr = w >> 1;
        short8 afq[4];
#pragma unroll
        for (int ks = 0; ks < 4; ks++)
            afq[ks] = ld8(&xfl[(st * 16 + lc) * 128 + (((ks * 4 + lg) ^ (lc & 7)) << 3)]);

        const float qscl = 0.18033688011112042f;  // 0.125 * log2(e)
        // Q then K: n-tiles hr*4..hr*4+3
#pragma unroll
        for (int qk = 0; qk < 2; qk++) {
            const u16* W = qk ? Wk : Wq;
            u16* dst = qk ? K : Q;
#pragma unroll
            for (int et = 0; et < 4; et++) {
                int nt = hr * 4 + et;
                f32x4 acc = {0.f, 0.f, 0.f, 0.f};
#pragma unroll
                for (int ks = 0; ks < 4; ks++) {
                    short8 bfr = ld8(W + (nt * 16 + lc) * 128 + ks * 32 + lg * 8);
                    acc = MFMA(afq[ks], bfr, acc);
                }
                int e = nt * 16 + lc, h = e >> 6, d = e & 63;
                float scl = qk ? 1.0f : qscl;
#pragma unroll
                for (int r = 0; r < 4; r++) {
                    int sr = sb + st * 16 + lg * 4 + r;
                    dst[(((size_t)b * 2 + h) * SEQ + sr) * 64 + d] = f2b(acc[r] * scl);
                }
            }
        }
        // V^T: A = Wv rows (d), B = xf rows (s) -> C col = s (coalesced V^T stores)
#pragma unroll
        for (int et = 0; et < 4; et++) {
            int nt = hr * 4 + et;
            f32x4 acc = {0.f, 0.f, 0.f, 0.f};
            short8 wv[4];
#pragma unroll
            for (int ks = 0; ks < 4; ks++)
                wv[ks] = ld8(Wv + (nt * 16 + lc) * 128 + ks * 32 + lg * 8);
#pragma unroll
            for (int ks = 0; ks < 4; ks++)
                acc = MFMA(wv[ks], afq[ks], acc);
#pragma unroll
            for (int r = 0; r < 4; r++) {
                int d = nt * 16 + lg * 4 + r, h = d >> 6, dd = d & 63;
                V[((size_t)(b * 2 + h) * 64 + dd) * SEQ + sb + st * 16 + lc] = f2b(acc[r]);
            }
        }
    }
}

// ---- K2: flash attention, split-K, swapped QK^T (scores lane-local per q-row). ----
__global__ __launch_bounds__(256) void k_attn(const u16* __restrict__ Q,
                                              const u16* __restrict__ K,
                                              const u16* __restrict__ Vg,
                                              u16* __restrict__ Op,
                                              float2* __restrict__ ml) {
    __shared__ __align__(16) u16 Klds[2][4096];   // [key 64][d 64] swizzled
    __shared__ __align__(16) u16 Vlds[2][4096];   // [d 64][key 64] swizzled
    __shared__ __align__(16) u16 Pl[4][16][64];   // per-wave P [q 16][key 64] swizzled
    int blk = blockIdx.x;
    int split = blk >> 8, bh = (blk >> 6) & 3, qb = (blk & 63) * 64;
    int kbase = split * (SEQ / KSPLIT);
    const u16* Qp = Q + (size_t)bh * SEQ * 64;
    const u16* Kp = K + (size_t)bh * SEQ * 64;
    const u16* Vp = Vg + (size_t)bh * SEQ * 64;   // (d, s)
    int t = threadIdx.x, w = t >> 6, l = t & 63, lc = l & 15, lg = l >> 4;
    uint32_t* plw = (uint32_t*)&Pl[w][0][0];      // row stride 32 u32

    int swz8 = ((l & 7) ^ ((l >> 3) & 7)) * 8;
    const u16* kSrc = Kp + (size_t)(kbase + w * 16 + (l >> 3)) * 64 + swz8;
    const u16* vSrc = Vp + (size_t)(w * 16 + (l >> 3)) * SEQ + kbase + swz8;

    short8 qa[2];
    qa[0] = ld8(Qp + (size_t)(qb + w * 16 + lc) * 64 + lg * 8);
    qa[1] = ld8(Qp + (size_t)(qb + w * 16 + lc) * 64 + 32 + lg * 8);

    f32x4 oacc[4];
#pragma unroll
    for (int i = 0; i < 4; i++) oacc[i] = (f32x4){0.f, 0.f, 0.f, 0.f};
    float m = -INFINITY, ls = 0.f;

    int c0 = (lg ^ (lc & 7)) * 8;

#define STAGE(buf, tt) do {                                           \
        const u16* ks_ = kSrc + (size_t)(tt) * 4096;                  \
        const u16* vs_ = vSrc + (tt) * 64;                            \
        gld16(ks_,           &Klds[buf][w * 1024]);                   \
        gld16(ks_ + 512,     &Klds[buf][w * 1024 + 512]);             \
        gld16(vs_,           &Vlds[buf][w * 1024]);                   \
        gld16(vs_ + 8 * SEQ, &Vlds[buf][w * 1024 + 512]);             \
    } while (0)

    STAGE(0, 0);
    __syncthreads();

    for (int tt = 0; tt < SEQ / KSPLIT / 64; tt++) {
        int cur = tt & 1;
        if (tt + 1 < SEQ / KSPLIT / 64) STAGE(cur ^ 1, tt + 1);

        const u16* kb = Klds[cur];
        const u16* vb = Vlds[cur];

        f32x4 sc[4];
#pragma unroll
        for (int nt = 0; nt < 4; nt++) {
            sc[nt] = (f32x4){0.f, 0.f, 0.f, 0.f};
            short8 kf0 = ld8(kb + (nt * 16 + lc) * 64 + c0);
            short8 kf1 = ld8(kb + (nt * 16 + lc) * 64 + (c0 ^ 32));
            sc[nt] = MFMA(kf0, qa[0], sc[nt]);
            sc[nt] = MFMA(kf1, qa[1], sc[nt]);
        }

        float mx = sc[0][0];
#pragma unroll
        for (int nt = 0; nt < 4; nt++)
#pragma unroll
            for (int r = 0; r < 4; r++) mx = fmaxf(mx, sc[nt][r]);
        mx = fmaxf(mx, __shfl_xor(mx, 16));
        mx = fmaxf(mx, __shfl_xor(mx, 32));

        if (__any(mx - m > 8.f)) {
            float mn = fmaxf(m, mx);
            float corr = exp2f(m - mn);
#pragma unroll
            for (int r = 0; r < 4; r++) {
                float cr = __shfl(corr, lg * 4 + r);
#pragma unroll
                for (int dt = 0; dt < 4; dt++) oacc[dt][r] *= cr;
            }
            ls *= corr;
            m = mn;
        }

        float rs = 0.f;
        uint32_t pk[8];
#pragma unroll
        for (int nt = 0; nt < 4; nt++) {
            float p0 = exp2f(sc[nt][0] - m), p1 = exp2f(sc[nt][1] - m);
            float p2 = exp2f(sc[nt][2] - m), p3 = exp2f(sc[nt][3] - m);
            rs += (p0 + p1) + (p2 + p3);
            pk[nt * 2]     = pk2(p0, p1);
            pk[nt * 2 + 1] = pk2(p2, p3);
        }
        rs += __shfl_xor(rs, 16);
        rs += __shfl_xor(rs, 32);
        ls += rs;

#pragma unroll
        for (int nt = 0; nt < 4; nt++) {
            int base = lc * 32 + (((nt * 2 + (lg >> 1)) ^ (lc & 7)) << 2) + (lg & 1) * 2;
            plw[base]     = pk[nt * 2];
            plw[base + 1] = pk[nt * 2 + 1];
        }

#pragma unroll
        for (int ks = 0; ks < 2; ks++) {
            short8 pa = ld8(&Pl[w][lc][(((ks * 4 + lg) ^ (lc & 7)) << 3)]);
#pragma unroll
            for (int dt = 0; dt < 4; dt++) {
                short8 vf = ld8(vb + (dt * 16 + lc) * 64 + (ks ? (c0 ^ 32) : c0));
                oacc[dt] = MFMA(pa, vf, oacc[dt]);
            }
        }
        __syncthreads();
    }
#undef STAGE

    size_t rowbase = (size_t)(split * 4 + bh) * SEQ + qb + w * 16;
#pragma unroll
    for (int dt = 0; dt < 4; dt++)
#pragma unroll
        for (int r = 0; r < 4; r++)
            Op[(rowbase + lg * 4 + r) * 64 + dt * 16 + lc] = f2b(oacc[dt][r]);
    if (l < 16) {
        float2 v; v.x = m; v.y = ls;
        ml[rowbase + lc] = v;
    }
}

// ---- K3: FUSED comb+out. Grid 256 = b*128 + sblk (32 s-rows).
//  Merge KSPLIT partials -> swizzled LDS O tile -> @ Wc^T + bc + gate*x -> out. ----
__global__ __launch_bounds__(256) void k_back(const u16* __restrict__ Op,
                                              const float2* __restrict__ ml,
                                              const u16* __restrict__ Wc,
                                              const float* __restrict__ bc,
                                              const float* __restrict__ x,
                                              const float* __restrict__ gate,
                                              float* __restrict__ out) {
    __shared__ __align__(16) u16 Ol[32 * 128];   // O tile, chunk-XOR swizzled
    int blk = blockIdx.x;
    int b = blk >> 7, sb = (blk & 127) * 32;
    int t = threadIdx.x, w = t >> 6, l = t & 63, lc = l & 15, lg = l >> 4;
    float g = gate[0];

    // step 1: merge partials. thread t -> s_local = t>>3, 16-col group ci = t&7
    {
        int sl = t >> 3, ci = t & 7;
        int h = ci >> 2, d0 = (ci & 3) * 16;
        size_t rp0 = ((size_t)(b * 2 + h) << 12) + sb + sl;
        float2 e0 = ml[rp0], e1 = ml[rp0 + 16384], e2 = ml[rp0 + 32768], e3 = ml[rp0 + 49152];
        float ms = fmaxf(fmaxf(e0.x, e1.x), fmaxf(e2.x, e3.x));
        float c0 = exp2f(e0.x - ms), c1 = exp2f(e1.x - ms);
        float c2 = exp2f(e2.x - ms), c3 = exp2f(e3.x - ms);
        float inv = 1.0f / (c0 * e0.y + c1 * e1.y + c2 * e2.y + c3 * e3.y);

        const u16* p0 = Op + rp0 * 64 + d0;
        const u16* p1 = p0 + (size_t)16384 * 64;
        const u16* p2 = p0 + (size_t)32768 * 64;
        const u16* p3 = p0 + (size_t)49152 * 64;
#pragma unroll
        for (int half = 0; half < 2; half++) {
            short8 a0 = ld8(p0 + half * 8), a1 = ld8(p1 + half * 8);
            short8 a2 = ld8(p2 + half * 8), a3 = ld8(p3 + half * 8);
            short8 ov;
#pragma unroll
            for (int e = 0; e < 8; e++) {
                float acc = c0 * b2f((u16)a0[e]) + c1 * b2f((u16)a1[e]) +
                            c2 * b2f((u16)a2[e]) + c3 * b2f((u16)a3[e]);
                ov[e] = (short)f2b(acc * inv);
            }
            int chunk = ci * 2 + half;
            *reinterpret_cast<short8*>(&Ol[sl * 128 + ((chunk ^ (sl & 7)) << 3)]) = ov;
        }
    }
    __syncthreads();

    // step 2: out = O @ Wc^T + bc + gate*x. Wave w -> co-tile w, s-tiles 0..1
    short8 af[4];
#pragma unroll
    for (int ks = 0; ks < 4; ks++)
        af[ks] = ld8(Wc + (w * 16 + lc) * 128 + ks * 32 + lg * 8);

#pragma unroll
    for (int st = 0; st < 2; st++) {
        f32x4 acc = {0.f, 0.f, 0.f, 0.f};
#pragma unroll
        for (int ks = 0; ks < 4; ks++) {
            short8 bfr = ld8(&Ol[(st * 16 + lc) * 128 + (((ks * 4 + lg) ^ (lc & 7)) << 3)]);
            acc = MFMA(af[ks], bfr, acc);
        }
#pragma unroll
        for (int r = 0; r < 4; r++) {
            int co = w * 16 + lg * 4 + r;
            int s = sb + st * 16 + lc;
            size_t idx = ((size_t)b * 64 + co) * SEQ + s;
            out[idx] = acc[r] + bc[co] + g * x[idx];
        }
    }
}

extern "C" void kernel_launch(void* const* d_in, const int* in_sizes, int n_in,
                              void* d_out, int out_size, void* d_ws, size_t ws_size,
                              hipStream_t stream) {
    const float* x    = (const float*)d_in[0];
    const float* Wcp  = (const float*)d_in[1];
    const float* bcp  = (const float*)d_in[2];
    const float* Wq   = (const float*)d_in[3];
    const float* Wk   = (const float*)d_in[4];
    const float* Wv   = (const float*)d_in[5];
    const float* Wo   = (const float*)d_in[6];
    const float* bo   = (const float*)d_in[7];
    const float* Wout = (const float*)d_in[8];
    const float* bout = (const float*)d_in[9];
    const float* pos  = (const float*)d_in[10];
    const float* gate = (const float*)d_in[11];

    char* ws = (char*)d_ws;
    float2* mlp  = (float2*)(ws);                        // [0,512KB) [4][4][4096] float2
    u16*    Qb   = (u16*)(ws + (2u << 20));              // [2,4) MB  (b,h,s,d) bf16
    u16*    Kb   = (u16*)(ws + (4u << 20));              // [4,6) MB
    u16*    Vt   = (u16*)(ws + (6u << 20));              // [6,8) MB  (b,h,d,s) bf16
    u16*    Wc   = (u16*)(ws + (10u << 20));             // 16 KB
    float*  bc   = (float*)(ws + (10u << 20) + 16384);   // 256 B
    u16*    Wcp_b = (u16*)(ws + (10u << 20) + 32768);    // 16 KB
    u16*    Wq_b  = (u16*)(ws + (10u << 20) + 49152);    // 32 KB
    u16*    Wk_b  = (u16*)(ws + (10u << 20) + 81920);    // 32 KB
    u16*    Wv_b  = (u16*)(ws + (10u << 20) + 114688);   // 32 KB
    u16*    Opb  = (u16*)(ws + (10u << 20) + (512u << 10)); // [10.5,18.5) MB bf16 partials
    float* out = (float*)d_out;

    hipLaunchKernelGGL(k_prep, dim3(257), dim3(256), 0, stream,
                       Wo, bo, Wout, bout, Wcp, Wq, Wk, Wv,
                       Wc, bc, Wcp_b, Wq_b, Wk_b, Wv_b);
    hipLaunchKernelGGL(k_front, dim3(256), dim3(256), 0, stream,
                       x, Wcp_b, bcp, pos, Wq_b, Wk_b, Wv_b, Qb, Kb, Vt);
    hipLaunchKernelGGL(k_attn, dim3(256 * KSPLIT), dim3(256), 0, stream, Qb, Kb, Vt, Opb, mlp);
    hipLaunchKernelGGL(k_back, dim3(256), dim3(256), 0, stream, Opb, mlp, Wc, bc, x, gate, out);
}

// Round 7
// 62.840 us; speedup vs baseline: 3.2757x; 1.0602x over previous
//
#include <hip/hip_runtime.h>
#include <hip/hip_bf16.h>
#include <cstdint>

typedef unsigned short u16;
typedef __attribute__((ext_vector_type(8))) short short8;
typedef __attribute__((ext_vector_type(8))) float f32x8;
typedef __attribute__((ext_vector_type(4))) float f32x4;

#define MFMA(a, b, c) __builtin_amdgcn_mfma_f32_16x16x32_bf16((a), (b), (c), 0, 0, 0)

// B=2, S=4096, E=128, NH=2, HD=64, CIN=64, COUT=64
#define SEQ 4096
#define KSPLIT 8
#define NT (SEQ / KSPLIT / 64)   // tiles per block = 8

static __device__ __forceinline__ float b2f(u16 u) {
    union { float f; uint32_t i; } c; c.i = ((uint32_t)u) << 16; return c.f;
}
static __device__ __forceinline__ u16 f2b(float f) {
    union { float f; uint32_t i; } c; c.f = f;
    uint32_t r = c.i + 0x7FFF + ((c.i >> 16) & 1);   // RNE f32->bf16
    return (u16)(r >> 16);
}
static __device__ __forceinline__ short8 ld8(const u16* p) {
    return *reinterpret_cast<const short8*>(p);
}
// pack two f32 -> bf16x2 word (lo = a, hi = b), RNE
static __device__ __forceinline__ uint32_t pk2(float a, float b) {
    uint32_t r;
    asm("v_cvt_pk_bf16_f32 %0, %1, %2" : "=v"(r) : "v"(a), "v"(b));
    return r;
}
// async global->LDS: per-lane global src, wave-uniform LDS base + lane*16B
static __device__ __forceinline__ void gld16(const u16* g, u16* l) {
    __builtin_amdgcn_global_load_lds(
        (const __attribute__((address_space(1))) unsigned int*)g,
        (__attribute__((address_space(3))) unsigned int*)l, 16, 0, 0);
}

// ---- K0: Wc = Wout @ Wo (bf16), bc = bo @ Wout^T + bout (f32); weights f32->bf16 ----
__global__ void k_prep(const float* __restrict__ Wo, const float* __restrict__ bo,
                       const float* __restrict__ Wout, const float* __restrict__ bout,
                       const float* __restrict__ Wcp, const float* __restrict__ Wq,
                       const float* __restrict__ Wk, const float* __restrict__ Wv,
                       u16* __restrict__ Wc, float* __restrict__ bc,
                       u16* __restrict__ Wcp_b, u16* __restrict__ Wq_b,
                       u16* __restrict__ Wk_b, u16* __restrict__ Wv_b) {
    int idx = blockIdx.x * 256 + threadIdx.x;
    if (idx < 8192) {
        int co = idx >> 7, e = idx & 127;
        float s = 0.f;
        for (int k = 0; k < 128; k++)
            s += Wout[co * 128 + k] * Wo[k * 128 + e];
        Wc[idx] = f2b(s);
    } else if (idx < 8256) {
        int co = idx - 8192;
        float s = bout[co];
        for (int k = 0; k < 128; k++)
            s += bo[k] * Wout[co * 128 + k];
        bc[co] = s;
    } else if (idx < 16448) {
        int i = idx - 8256;  Wcp_b[i] = f2b(Wcp[i]);
    } else if (idx < 32832) {
        int i = idx - 16448; Wq_b[i] = f2b(Wq[i]);
    } else if (idx < 49216) {
        int i = idx - 32832; Wk_b[i] = f2b(Wk[i]);
    } else if (idx < 65600) {
        int i = idx - 49216; Wv_b[i] = f2b(Wv[i]);
    }
}

// ---- K1: FUSED embed+qkv. Grid 256 = b*128 + sblk (32 s-rows each). ----
__global__ __launch_bounds__(256) void k_front(const float* __restrict__ x,
                                               const u16* __restrict__ Wcp,
                                               const float* __restrict__ bcp,
                                               const float* __restrict__ pos,
                                               const u16* __restrict__ Wq,
                                               const u16* __restrict__ Wk,
                                               const u16* __restrict__ Wv,
                                               u16* __restrict__ Q, u16* __restrict__ K,
                                               u16* __restrict__ V) {
    __shared__ __align__(16) u16 xT[32][72];     // [s][c] transposed input
    __shared__ __align__(16) u16 xfl[32 * 128];  // xf tile, chunk-XOR swizzled
    int blk = blockIdx.x;
    int b = blk >> 7, sb = (blk & 127) * 32;
    int t = threadIdx.x, w = t >> 6, l = t & 63, lc = l & 15, lg = l >> 4;

    {
        int c = t & 63, so = t >> 6;
        const float* src = x + ((size_t)b * 64 + c) * SEQ + sb + so * 8;
        f32x8 a0 = *reinterpret_cast<const f32x8*>(src);
#pragma unroll
        for (int j = 0; j < 8; j++) xT[so * 8 + j][c] = f2b(a0[j]);
    }
    __syncthreads();

    // phase 1: xf = xT @ Wcp^T + bcp + pos  -> swizzled LDS
    {
        int rt = w >> 1, eh = w & 1;
        short8 af[2];
        af[0] = ld8(&xT[rt * 16 + lc][lg * 8]);
        af[1] = ld8(&xT[rt * 16 + lc][32 + lg * 8]);
#pragma unroll
        for (int et = 0; et < 4; et++) {
            int nt = eh * 4 + et;
            f32x4 acc = {0.f, 0.f, 0.f, 0.f};
#pragma unroll
            for (int ks = 0; ks < 2; ks++) {
                short8 bfr = ld8(Wcp + (nt * 16 + lc) * 64 + ks * 32 + lg * 8);
                acc = MFMA(af[ks], bfr, acc);
            }
            int e = nt * 16 + lc;
            float be = bcp[e];
            int chunk = e >> 3;
#pragma unroll
            for (int r = 0; r < 4; r++) {
                int sl = rt * 16 + lg * 4 + r;
                float v = acc[r] + be + pos[(size_t)(sb + sl) * 128 + e];
                xfl[sl * 128 + ((chunk ^ (sl & 7)) << 3) + (e & 7)] = f2b(v);
            }
        }
    }
    __syncthreads();

    // phase 2: Q/K/V from LDS xf
    {
        int st = w & 1, hr = w >> 1;
        short8 afq[4];
#pragma unroll
        for (int ks = 0; ks < 4; ks++)
            afq[ks] = ld8(&xfl[(st * 16 + lc) * 128 + (((ks * 4 + lg) ^ (lc & 7)) << 3)]);

        const float qscl = 0.18033688011112042f;  // 0.125 * log2(e)
#pragma unroll
        for (int qk = 0; qk < 2; qk++) {
            const u16* W = qk ? Wk : Wq;
            u16* dst = qk ? K : Q;
#pragma unroll
            for (int et = 0; et < 4; et++) {
                int nt = hr * 4 + et;
                f32x4 acc = {0.f, 0.f, 0.f, 0.f};
#pragma unroll
                for (int ks = 0; ks < 4; ks++) {
                    short8 bfr = ld8(W + (nt * 16 + lc) * 128 + ks * 32 + lg * 8);
                    acc = MFMA(afq[ks], bfr, acc);
                }
                int e = nt * 16 + lc, h = e >> 6, d = e & 63;
                float scl = qk ? 1.0f : qscl;
#pragma unroll
                for (int r = 0; r < 4; r++) {
                    int sr = sb + st * 16 + lg * 4 + r;
                    dst[(((size_t)b * 2 + h) * SEQ + sr) * 64 + d] = f2b(acc[r] * scl);
                }
            }
        }
        // V^T: A = Wv rows (d), B = xf rows (s) -> coalesced V^T stores
#pragma unroll
        for (int et = 0; et < 4; et++) {
            int nt = hr * 4 + et;
            f32x4 acc = {0.f, 0.f, 0.f, 0.f};
            short8 wv[4];
#pragma unroll
            for (int ks = 0; ks < 4; ks++)
                wv[ks] = ld8(Wv + (nt * 16 + lc) * 128 + ks * 32 + lg * 8);
#pragma unroll
            for (int ks = 0; ks < 4; ks++)
                acc = MFMA(wv[ks], afq[ks], acc);
#pragma unroll
            for (int r = 0; r < 4; r++) {
                int d = nt * 16 + lg * 4 + r, h = d >> 6, dd = d & 63;
                V[((size_t)(b * 2 + h) * 64 + dd) * SEQ + sb + st * 16 + lc] = f2b(acc[r]);
            }
        }
    }
}

// ---- K2: flash attention, split-K=8, swapped QK^T, lane-local deferred max,
//  ls via ones-MFMA (offloaded to matrix pipe). ----
__global__ __launch_bounds__(256) void k_attn(const u16* __restrict__ Q,
                                              const u16* __restrict__ K,
                                              const u16* __restrict__ Vg,
                                              u16* __restrict__ Op,
                                              float2* __restrict__ ml) {
    __shared__ __align__(16) u16 Klds[2][4096];   // [key 64][d 64] swizzled
    __shared__ __align__(16) u16 Vlds[2][4096];   // [d 64][key 64] swizzled
    __shared__ __align__(16) u16 Pl[4][16][64];   // per-wave P [q 16][key 64] swizzled
    int blk = blockIdx.x;
    int split = blk >> 8, bh = (blk >> 6) & 3, qb = (blk & 63) * 64;
    int kbase = split * (SEQ / KSPLIT);
    const u16* Qp = Q + (size_t)bh * SEQ * 64;
    const u16* Kp = K + (size_t)bh * SEQ * 64;
    const u16* Vp = Vg + (size_t)bh * SEQ * 64;   // (d, s)
    int t = threadIdx.x, w = t >> 6, l = t & 63, lc = l & 15, lg = l >> 4;
    uint32_t* plw = (uint32_t*)&Pl[w][0][0];      // row stride 32 u32

    int swz8 = ((l & 7) ^ ((l >> 3) & 7)) * 8;
    const u16* kSrc = Kp + (size_t)(kbase + w * 16 + (l >> 3)) * 64 + swz8;
    const u16* vSrc = Vp + (size_t)(w * 16 + (l >> 3)) * SEQ + kbase + swz8;

    short8 qa[2];
    qa[0] = ld8(Qp + (size_t)(qb + w * 16 + lc) * 64 + lg * 8);
    qa[1] = ld8(Qp + (size_t)(qb + w * 16 + lc) * 64 + 32 + lg * 8);

    short8 onesb;   // bf16 1.0 B-fragment for row-sum MFMA
#pragma unroll
    for (int i = 0; i < 8; i++) onesb[i] = (short)0x3F80;

    f32x4 oacc[4], lsacc = {0.f, 0.f, 0.f, 0.f};
#pragma unroll
    for (int i = 0; i < 4; i++) oacc[i] = (f32x4){0.f, 0.f, 0.f, 0.f};
    float m = -INFINITY;

    int c0 = (lg ^ (lc & 7)) * 8;

#define STAGE(buf, tt) do {                                           \
        const u16* ks_ = kSrc + (size_t)(tt) * 4096;                  \
        const u16* vs_ = vSrc + (tt) * 64;                            \
        gld16(ks_,           &Klds[buf][w * 1024]);                   \
        gld16(ks_ + 512,     &Klds[buf][w * 1024 + 512]);             \
        gld16(vs_,           &Vlds[buf][w * 1024]);                   \
        gld16(vs_ + 8 * SEQ, &Vlds[buf][w * 1024 + 512]);             \
    } while (0)

    STAGE(0, 0);
    __syncthreads();

#pragma unroll 2
    for (int tt = 0; tt < NT; tt++) {
        int cur = tt & 1;
        if (tt + 1 < NT) STAGE(cur ^ 1, tt + 1);

        const u16* kb = Klds[cur];
        const u16* vb = Vlds[cur];

        // scores, swapped: sc[nt][r] = S[key = nt*16 + lg*4 + r][q = lc]
        f32x4 sc[4];
#pragma unroll
        for (int nt = 0; nt < 4; nt++) {
            sc[nt] = (f32x4){0.f, 0.f, 0.f, 0.f};
            short8 kf0 = ld8(kb + (nt * 16 + lc) * 64 + c0);
            short8 kf1 = ld8(kb + (nt * 16 + lc) * 64 + (c0 ^ 32));
            sc[nt] = MFMA(kf0, qa[0], sc[nt]);
            sc[nt] = MFMA(kf1, qa[1], sc[nt]);
        }

        // lane-local max (no cross-lane shuffles on the common path)
        float mx = fmaxf(fmaxf(sc[0][0], sc[0][1]), fmaxf(sc[0][2], sc[0][3]));
#pragma unroll
        for (int nt = 1; nt < 4; nt++)
            mx = fmaxf(mx, fmaxf(fmaxf(sc[nt][0], sc[nt][1]),
                                 fmaxf(sc[nt][2], sc[nt][3])));

        // deferred rescale: trigger only when any lane's local max grows > 8 (log2)
        if (__any(mx - m > 8.f)) {
            float mr = fmaxf(mx, __shfl_xor(mx, 16));
            mr = fmaxf(mr, __shfl_xor(mr, 32));
            float mn = fmaxf(m, mr);
            float corr = exp2f(m - mn);   // first tile: exp2(-inf)=0
#pragma unroll
            for (int r = 0; r < 4; r++) {
                float cr = __shfl(corr, lg * 4 + r);
#pragma unroll
                for (int dt = 0; dt < 4; dt++) oacc[dt][r] *= cr;
                lsacc[r] *= cr;
            }
            m = mn;
        }

        // exp2 + pack P (bounded by 2^8)
        uint32_t pk[8];
#pragma unroll
        for (int nt = 0; nt < 4; nt++) {
            float p0 = exp2f(sc[nt][0] - m), p1 = exp2f(sc[nt][1] - m);
            float p2 = exp2f(sc[nt][2] - m), p3 = exp2f(sc[nt][3] - m);
            pk[nt * 2]     = pk2(p0, p1);
            pk[nt * 2 + 1] = pk2(p2, p3);
        }
#pragma unroll
        for (int nt = 0; nt < 4; nt++) {
            int base = lc * 32 + (((nt * 2 + (lg >> 1)) ^ (lc & 7)) << 2) + (lg & 1) * 2;
            uint2 u; u.x = pk[nt * 2]; u.y = pk[nt * 2 + 1];
            *reinterpret_cast<uint2*>(&plw[base]) = u;
        }

        // O += P @ V ; ls += P @ ones (matrix pipe)
#pragma unroll
        for (int ks = 0; ks < 2; ks++) {
            short8 pa = ld8(&Pl[w][lc][(((ks * 4 + lg) ^ (lc & 7)) << 3)]);
            lsacc = MFMA(pa, onesb, lsacc);
#pragma unroll
            for (int dt = 0; dt < 4; dt++) {
                short8 vf = ld8(vb + (dt * 16 + lc) * 64 + (ks ? (c0 ^ 32) : c0));
                oacc[dt] = MFMA(pa, vf, oacc[dt]);
            }
        }
        __syncthreads();
    }
#undef STAGE

    // epilogue: unnormalized bf16 partials + per-row (m, ls)
    size_t rowbase = (size_t)(split * 4 + bh) * SEQ + qb + w * 16;
#pragma unroll
    for (int dt = 0; dt < 4; dt++)
#pragma unroll
        for (int r = 0; r < 4; r++)
            Op[(rowbase + lg * 4 + r) * 64 + dt * 16 + lc] = f2b(oacc[dt][r]);
    float mrow[4];
#pragma unroll
    for (int r = 0; r < 4; r++) mrow[r] = __shfl(m, lg * 4 + r);
    if (lc == 0) {
#pragma unroll
        for (int r = 0; r < 4; r++) {
            float2 v; v.x = mrow[r]; v.y = lsacc[r];
            ml[rowbase + lg * 4 + r] = v;
        }
    }
}

// ---- K3: FUSED comb+out. Grid 256 = b*128 + sblk (32 s-rows). 8-way merge. ----
__global__ __launch_bounds__(256) void k_back(const u16* __restrict__ Op,
                                              const float2* __restrict__ ml,
                                              const u16* __restrict__ Wc,
                                              const float* __restrict__ bc,
                                              const float* __restrict__ x,
                                              const float* __restrict__ gate,
                                              float* __restrict__ out) {
    __shared__ __align__(16) u16 Ol[32 * 128];   // O tile, chunk-XOR swizzled
    int blk = blockIdx.x;
    int b = blk >> 7, sb = (blk & 127) * 32;
    int t = threadIdx.x, w = t >> 6, l = t & 63, lc = l & 15, lg = l >> 4;
    float g = gate[0];

    {
        int sl = t >> 3, ci = t & 7;
        int h = ci >> 2, d0 = (ci & 3) * 16;
        size_t rp0 = ((size_t)(b * 2 + h) << 12) + sb + sl;
        float2 e[KSPLIT];
        float ms = -INFINITY;
#pragma unroll
        for (int k = 0; k < KSPLIT; k++) {
            e[k] = ml[rp0 + (size_t)k * 16384];
            ms = fmaxf(ms, e[k].x);
        }
        float den = 0.f, c[KSPLIT];
#pragma unroll
        for (int k = 0; k < KSPLIT; k++) {
            c[k] = exp2f(e[k].x - ms);
            den += c[k] * e[k].y;
        }
        float inv = 1.0f / den;
#pragma unroll
        for (int half = 0; half < 2; half++) {
            float acc[8];
#pragma unroll
            for (int j = 0; j < 8; j++) acc[j] = 0.f;
#pragma unroll
            for (int k = 0; k < KSPLIT; k++) {
                short8 a = ld8(Op + (rp0 + (size_t)k * 16384) * 64 + d0 + half * 8);
#pragma unroll
                for (int j = 0; j < 8; j++) acc[j] += c[k] * b2f((u16)a[j]);
            }
            short8 ov;
#pragma unroll
            for (int j = 0; j < 8; j++) ov[j] = (short)f2b(acc[j] * inv);
            int chunk = ci * 2 + half;
            *reinterpret_cast<short8*>(&Ol[sl * 128 + ((chunk ^ (sl & 7)) << 3)]) = ov;
        }
    }
    __syncthreads();

    // out = O @ Wc^T + bc + gate*x
    short8 af[4];
#pragma unroll
    for (int ks = 0; ks < 4; ks++)
        af[ks] = ld8(Wc + (w * 16 + lc) * 128 + ks * 32 + lg * 8);

#pragma unroll
    for (int st = 0; st < 2; st++) {
        f32x4 acc = {0.f, 0.f, 0.f, 0.f};
#pragma unroll
        for (int ks = 0; ks < 4; ks++) {
            short8 bfr = ld8(&Ol[(st * 16 + lc) * 128 + (((ks * 4 + lg) ^ (lc & 7)) << 3)]);
            acc = MFMA(af[ks], bfr, acc);
        }
#pragma unroll
        for (int r = 0; r < 4; r++) {
            int co = w * 16 + lg * 4 + r;
            int s = sb + st * 16 + lc;
            size_t idx = ((size_t)b * 64 + co) * SEQ + s;
            out[idx] = acc[r] + bc[co] + g * x[idx];
        }
    }
}

extern "C" void kernel_launch(void* const* d_in, const int* in_sizes, int n_in,
                              void* d_out, int out_size, void* d_ws, size_t ws_size,
                              hipStream_t stream) {
    const float* x    = (const float*)d_in[0];
    const float* Wcp  = (const float*)d_in[1];
    const float* bcp  = (const float*)d_in[2];
    const float* Wq   = (const float*)d_in[3];
    const float* Wk   = (const float*)d_in[4];
    const float* Wv   = (const float*)d_in[5];
    const float* Wo   = (const float*)d_in[6];
    const float* bo   = (const float*)d_in[7];
    const float* Wout = (const float*)d_in[8];
    const float* bout = (const float*)d_in[9];
    const float* pos  = (const float*)d_in[10];
    const float* gate = (const float*)d_in[11];

    char* ws = (char*)d_ws;
    float2* mlp  = (float2*)(ws);                        // [0,1MB)  [8][4][4096] float2
    u16*    Qb   = (u16*)(ws + (2u << 20));              // [2,4) MB  (b,h,s,d) bf16
    u16*    Kb   = (u16*)(ws + (4u << 20));              // [4,6) MB
    u16*    Vt   = (u16*)(ws + (6u << 20));              // [6,8) MB  (b,h,d,s) bf16
    u16*    Wc   = (u16*)(ws + (10u << 20));             // 16 KB
    float*  bc   = (float*)(ws + (10u << 20) + 16384);   // 256 B
    u16*    Wcp_b = (u16*)(ws + (10u << 20) + 32768);    // 16 KB
    u16*    Wq_b  = (u16*)(ws + (10u << 20) + 49152);    // 32 KB
    u16*    Wk_b  = (u16*)(ws + (10u << 20) + 81920);    // 32 KB
    u16*    Wv_b  = (u16*)(ws + (10u << 20) + 114688);   // 32 KB
    u16*    Opb  = (u16*)(ws + (10u << 20) + (512u << 10)); // [10.5,26.5) MB bf16 partials
    float* out = (float*)d_out;

    hipLaunchKernelGGL(k_prep, dim3(257), dim3(256), 0, stream,
                       Wo, bo, Wout, bout, Wcp, Wq, Wk, Wv,
                       Wc, bc, Wcp_b, Wq_b, Wk_b, Wv_b);
    hipLaunchKernelGGL(k_front, dim3(256), dim3(256), 0, stream,
                       x, Wcp_b, bcp, pos, Wq_b, Wk_b, Wv_b, Qb, Kb, Vt);
    hipLaunchKernelGGL(k_attn, dim3(256 * KSPLIT), dim3(256), 0, stream, Qb, Kb, Vt, Opb, mlp);
    hipLaunchKernelGGL(k_back, dim3(256), dim3(256), 0, stream, Opb, mlp, Wc, bc, x, gate, out);
}

// Round 8
// 61.816 us; speedup vs baseline: 3.3300x; 1.0166x over previous
//
#include <hip/hip_runtime.h>
#include <hip/hip_bf16.h>
#include <cstdint>

typedef unsigned short u16;
typedef __attribute__((ext_vector_type(8))) short short8;
typedef __attribute__((ext_vector_type(8))) float f32x8;
typedef __attribute__((ext_vector_type(4))) float f32x4;

#define MFMA(a, b, c) __builtin_amdgcn_mfma_f32_16x16x32_bf16((a), (b), (c), 0, 0, 0)

// B=2, S=4096, E=128, NH=2, HD=64, CIN=64, COUT=64
#define SEQ 4096
#define KSPLIT 8
#define NTILE (SEQ / KSPLIT / 32)   // 32-key tiles per block = 16

static __device__ __forceinline__ float b2f(u16 u) {
    union { float f; uint32_t i; } c; c.i = ((uint32_t)u) << 16; return c.f;
}
static __device__ __forceinline__ u16 f2b(float f) {
    union { float f; uint32_t i; } c; c.f = f;
    uint32_t r = c.i + 0x7FFF + ((c.i >> 16) & 1);   // RNE f32->bf16
    return (u16)(r >> 16);
}
static __device__ __forceinline__ short8 ld8(const u16* p) {
    return *reinterpret_cast<const short8*>(p);
}
// pack two f32 -> bf16x2 word (lo = a, hi = b), RNE
static __device__ __forceinline__ uint32_t pk2(float a, float b) {
    uint32_t r;
    asm("v_cvt_pk_bf16_f32 %0, %1, %2" : "=v"(r) : "v"(a), "v"(b));
    return r;
}
// async global->LDS: per-lane global src, wave-uniform LDS base + lane*16B
static __device__ __forceinline__ void gld16(const u16* g, u16* l) {
    __builtin_amdgcn_global_load_lds(
        (const __attribute__((address_space(1))) unsigned int*)g,
        (__attribute__((address_space(3))) unsigned int*)l, 16, 0, 0);
}

// ---- K0: Wc = Wout @ Wo (bf16), bc = bo @ Wout^T + bout (f32); weights f32->bf16 ----
__global__ void k_prep(const float* __restrict__ Wo, const float* __restrict__ bo,
                       const float* __restrict__ Wout, const float* __restrict__ bout,
                       const float* __restrict__ Wcp, const float* __restrict__ Wq,
                       const float* __restrict__ Wk, const float* __restrict__ Wv,
                       u16* __restrict__ Wc, float* __restrict__ bc,
                       u16* __restrict__ Wcp_b, u16* __restrict__ Wq_b,
                       u16* __restrict__ Wk_b, u16* __restrict__ Wv_b) {
    int idx = blockIdx.x * 256 + threadIdx.x;
    if (idx < 8192) {
        int co = idx >> 7, e = idx & 127;
        float s = 0.f;
        for (int k = 0; k < 128; k++)
            s += Wout[co * 128 + k] * Wo[k * 128 + e];
        Wc[idx] = f2b(s);
    } else if (idx < 8256) {
        int co = idx - 8192;
        float s = bout[co];
        for (int k = 0; k < 128; k++)
            s += bo[k] * Wout[co * 128 + k];
        bc[co] = s;
    } else if (idx < 16448) {
        int i = idx - 8256;  Wcp_b[i] = f2b(Wcp[i]);
    } else if (idx < 32832) {
        int i = idx - 16448; Wq_b[i] = f2b(Wq[i]);
    } else if (idx < 49216) {
        int i = idx - 32832; Wk_b[i] = f2b(Wk[i]);
    } else if (idx < 65600) {
        int i = idx - 49216; Wv_b[i] = f2b(Wv[i]);
    }
}

// ---- K1: FUSED embed+qkv. Grid 256 = b*128 + sblk (32 s-rows each). ----
__global__ __launch_bounds__(256) void k_front(const float* __restrict__ x,
                                               const u16* __restrict__ Wcp,
                                               const float* __restrict__ bcp,
                                               const float* __restrict__ pos,
                                               const u16* __restrict__ Wq,
                                               const u16* __restrict__ Wk,
                                               const u16* __restrict__ Wv,
                                               u16* __restrict__ Q, u16* __restrict__ K,
                                               u16* __restrict__ V) {
    __shared__ __align__(16) u16 xT[32][72];     // [s][c] transposed input
    __shared__ __align__(16) u16 xfl[32 * 128];  // xf tile, chunk-XOR swizzled
    int blk = blockIdx.x;
    int b = blk >> 7, sb = (blk & 127) * 32;
    int t = threadIdx.x, w = t >> 6, l = t & 63, lc = l & 15, lg = l >> 4;

    {
        int c = t & 63, so = t >> 6;
        const float* src = x + ((size_t)b * 64 + c) * SEQ + sb + so * 8;
        f32x8 a0 = *reinterpret_cast<const f32x8*>(src);
#pragma unroll
        for (int j = 0; j < 8; j++) xT[so * 8 + j][c] = f2b(a0[j]);
    }
    __syncthreads();

    // phase 1: xf = xT @ Wcp^T + bcp + pos  -> swizzled LDS
    {
        int rt = w >> 1, eh = w & 1;
        short8 af[2];
        af[0] = ld8(&xT[rt * 16 + lc][lg * 8]);
        af[1] = ld8(&xT[rt * 16 + lc][32 + lg * 8]);
#pragma unroll
        for (int et = 0; et < 4; et++) {
            int nt = eh * 4 + et;
            f32x4 acc = {0.f, 0.f, 0.f, 0.f};
#pragma unroll
            for (int ks = 0; ks < 2; ks++) {
                short8 bfr = ld8(Wcp + (nt * 16 + lc) * 64 + ks * 32 + lg * 8);
                acc = MFMA(af[ks], bfr, acc);
            }
            int e = nt * 16 + lc;
            float be = bcp[e];
            int chunk = e >> 3;
#pragma unroll
            for (int r = 0; r < 4; r++) {
                int sl = rt * 16 + lg * 4 + r;
                float v = acc[r] + be + pos[(size_t)(sb + sl) * 128 + e];
                xfl[sl * 128 + ((chunk ^ (sl & 7)) << 3) + (e & 7)] = f2b(v);
            }
        }
    }
    __syncthreads();

    // phase 2: Q/K/V from LDS xf
    {
        int st = w & 1, hr = w >> 1;
        short8 afq[4];
#pragma unroll
        for (int ks = 0; ks < 4; ks++)
            afq[ks] = ld8(&xfl[(st * 16 + lc) * 128 + (((ks * 4 + lg) ^ (lc & 7)) << 3)]);

        const float qscl = 0.18033688011112042f;  // 0.125 * log2(e)
#pragma unroll
        for (int qk = 0; qk < 2; qk++) {
            const u16* W = qk ? Wk : Wq;
            u16* dst = qk ? K : Q;
#pragma unroll
            for (int et = 0; et < 4; et++) {
                int nt = hr * 4 + et;
                f32x4 acc = {0.f, 0.f, 0.f, 0.f};
#pragma unroll
                for (int ks = 0; ks < 4; ks++) {
                    short8 bfr = ld8(W + (nt * 16 + lc) * 128 + ks * 32 + lg * 8);
                    acc = MFMA(afq[ks], bfr, acc);
                }
                int e = nt * 16 + lc, h = e >> 6, d = e & 63;
                float scl = qk ? 1.0f : qscl;
#pragma unroll
                for (int r = 0; r < 4; r++) {
                    int sr = sb + st * 16 + lg * 4 + r;
                    dst[(((size_t)b * 2 + h) * SEQ + sr) * 64 + d] = f2b(acc[r] * scl);
                }
            }
        }
        // V^T: A = Wv rows (d), B = xf rows (s) -> coalesced V^T stores
#pragma unroll
        for (int et = 0; et < 4; et++) {
            int nt = hr * 4 + et;
            f32x4 acc = {0.f, 0.f, 0.f, 0.f};
            short8 wv[4];
#pragma unroll
            for (int ks = 0; ks < 4; ks++)
                wv[ks] = ld8(Wv + (nt * 16 + lc) * 128 + ks * 32 + lg * 8);
#pragma unroll
            for (int ks = 0; ks < 4; ks++)
                acc = MFMA(wv[ks], afq[ks], acc);
#pragma unroll
            for (int r = 0; r < 4; r++) {
                int d = nt * 16 + lg * 4 + r, h = d >> 6, dd = d & 63;
                V[((size_t)(b * 2 + h) * 64 + dd) * SEQ + sb + st * 16 + lc] = f2b(acc[r]);
            }
        }
    }
}

// ---- K2: flash attention, split-K=8, 32-key tiles, 20KB LDS -> 8 blocks/CU.
//  Swapped QK^T (lane-local q-rows), lane-local deferred max, ls via ones-MFMA. ----
__global__ __launch_bounds__(256, 8) void k_attn(const u16* __restrict__ Q,
                                                 const u16* __restrict__ K,
                                                 const u16* __restrict__ Vg,
                                                 u16* __restrict__ Op,
                                                 float2* __restrict__ ml) {
    __shared__ __align__(16) u16 Klds[2][2048];   // [key 32][d 64], chunk^(row&7)
    __shared__ __align__(16) u16 Vlds[2][2048];   // [d 64][key 32], chunk^((row>>1)&3)
    __shared__ __align__(16) u16 Pl[4][16][32];   // per-wave P, chunk^((q>>1)&3)
    int blk = blockIdx.x;
    int split = blk >> 8, bh = (blk >> 6) & 3, qb = (blk & 63) * 64;
    int kbase = split * (SEQ / KSPLIT);
    const u16* Qp = Q + (size_t)bh * SEQ * 64;
    const u16* Kp = K + (size_t)bh * SEQ * 64;
    const u16* Vp = Vg + (size_t)bh * SEQ * 64;   // (d, s)
    int t = threadIdx.x, w = t >> 6, l = t & 63, lc = l & 15, lg = l >> 4;
    uint32_t* plw = (uint32_t*)&Pl[w][0][0];      // row stride 16 u32

    // staging (pre-swizzled sources; LDS dest linear = base + lane*16B):
    // K: wave w rows w*8..w*8+7; lane row l>>3, phys chunk l&7 -> logical (l&7)^(l>>3)
    const u16* kSrc = Kp + (size_t)(kbase + w * 8 + (l >> 3)) * 64 + (((l & 7) ^ (l >> 3)) << 3);
    // V: wave w d-rows w*16..+15; lane row l>>2, phys chunk l&3 -> logical (l&3)^((l>>3)&3)
    const u16* vSrc = Vp + (size_t)(w * 16 + (l >> 2)) * SEQ + kbase + (((l & 3) ^ ((l >> 3) & 3)) << 3);

    short8 qa[2];
    qa[0] = ld8(Qp + (size_t)(qb + w * 16 + lc) * 64 + lg * 8);
    qa[1] = ld8(Qp + (size_t)(qb + w * 16 + lc) * 64 + 32 + lg * 8);

    short8 onesb;   // bf16 1.0 B-fragment for row-sum MFMA
#pragma unroll
    for (int i = 0; i < 8; i++) onesb[i] = (short)0x3F80;

    f32x4 oacc[4], lsacc = {0.f, 0.f, 0.f, 0.f};
#pragma unroll
    for (int i = 0; i < 4; i++) oacc[i] = (f32x4){0.f, 0.f, 0.f, 0.f};
    float m = -INFINITY;

    int c0 = (lg ^ (lc & 7)) * 8;           // K-frag swizzled offset (8-chunk rows)
    int cv = (lg ^ ((lc >> 1) & 3)) * 8;    // V/P-frag swizzled offset (4-chunk rows)

#define STAGE(buf, tt) do {                                       \
        gld16(kSrc + (size_t)(tt) * 2048, &Klds[buf][w * 512]);   \
        gld16(vSrc + (tt) * 32,           &Vlds[buf][w * 512]);   \
    } while (0)

    STAGE(0, 0);
    __syncthreads();

#pragma unroll 2
    for (int tt = 0; tt < NTILE; tt++) {
        int cur = tt & 1;
        if (tt + 1 < NTILE) STAGE(cur ^ 1, tt + 1);

        const u16* kb = Klds[cur];
        const u16* vb = Vlds[cur];

        // scores, swapped: sc[nt][r] = S[key = nt*16 + lg*4 + r][q = lc]
        f32x4 sc[2];
#pragma unroll
        for (int nt = 0; nt < 2; nt++) {
            sc[nt] = (f32x4){0.f, 0.f, 0.f, 0.f};
            short8 kf0 = ld8(kb + (nt * 16 + lc) * 64 + c0);
            short8 kf1 = ld8(kb + (nt * 16 + lc) * 64 + (c0 ^ 32));
            sc[nt] = MFMA(kf0, qa[0], sc[nt]);
            sc[nt] = MFMA(kf1, qa[1], sc[nt]);
        }

        // lane-local max (max3-fusible tree)
        float mx = fmaxf(fmaxf(fmaxf(sc[0][0], sc[0][1]), fmaxf(sc[0][2], sc[0][3])),
                         fmaxf(fmaxf(sc[1][0], sc[1][1]), fmaxf(sc[1][2], sc[1][3])));

        // deferred rescale: trigger only when any lane's local max grows > 8 (log2)
        if (__any(mx - m > 8.f)) {
            float mr = fmaxf(mx, __shfl_xor(mx, 16));
            mr = fmaxf(mr, __shfl_xor(mr, 32));
            float mn = fmaxf(m, mr);
            float corr = exp2f(m - mn);   // first tile: exp2(-inf)=0
#pragma unroll
            for (int r = 0; r < 4; r++) {
                float cr = __shfl(corr, lg * 4 + r);
#pragma unroll
                for (int dt = 0; dt < 4; dt++) oacc[dt][r] *= cr;
                lsacc[r] *= cr;
            }
            m = mn;
        }

        // exp2 + pack P (bounded by 2^8)
        uint32_t pk0 = pk2(exp2f(sc[0][0] - m), exp2f(sc[0][1] - m));
        uint32_t pk1 = pk2(exp2f(sc[0][2] - m), exp2f(sc[0][3] - m));
        uint32_t pk2w = pk2(exp2f(sc[1][0] - m), exp2f(sc[1][1] - m));
        uint32_t pk3 = pk2(exp2f(sc[1][2] - m), exp2f(sc[1][3] - m));

        // store packed P: row q=lc; nt=0 keys lg*4.., nt=1 keys 16+lg*4..
        {
            int rb2 = lc * 16 + (lg & 1) * 2;
            int ph0 = ((lg >> 1) ^ ((lc >> 1) & 3)) * 4;
            int ph1 = ((2 + (lg >> 1)) ^ ((lc >> 1) & 3)) * 4;
            uint2 u0; u0.x = pk0; u0.y = pk1;
            uint2 u1; u1.x = pk2w; u1.y = pk3;
            *reinterpret_cast<uint2*>(&plw[rb2 + ph0]) = u0;
            *reinterpret_cast<uint2*>(&plw[rb2 + ph1]) = u1;
        }

        // O += P @ V ; ls += P @ ones (matrix pipe)
        short8 pa = ld8(&Pl[w][lc][cv]);
        lsacc = MFMA(pa, onesb, lsacc);
#pragma unroll
        for (int dt = 0; dt < 4; dt++) {
            short8 vf = ld8(vb + (dt * 16 + lc) * 32 + cv);
            oacc[dt] = MFMA(pa, vf, oacc[dt]);
        }
        __syncthreads();
    }
#undef STAGE

    // epilogue: unnormalized bf16 partials + per-row (m, ls)
    size_t rowbase = (size_t)(split * 4 + bh) * SEQ + qb + w * 16;
#pragma unroll
    for (int dt = 0; dt < 4; dt++)
#pragma unroll
        for (int r = 0; r < 4; r++)
            Op[(rowbase + lg * 4 + r) * 64 + dt * 16 + lc] = f2b(oacc[dt][r]);
    float mrow[4];
#pragma unroll
    for (int r = 0; r < 4; r++) mrow[r] = __shfl(m, lg * 4 + r);
    if (lc == 0) {
#pragma unroll
        for (int r = 0; r < 4; r++) {
            float2 v; v.x = mrow[r]; v.y = lsacc[r];
            ml[rowbase + lg * 4 + r] = v;
        }
    }
}

// ---- K3: FUSED comb+out. Grid 256 = b*128 + sblk (32 s-rows). 8-way merge. ----
__global__ __launch_bounds__(256) void k_back(const u16* __restrict__ Op,
                                              const float2* __restrict__ ml,
                                              const u16* __restrict__ Wc,
                                              const float* __restrict__ bc,
                                              const float* __restrict__ x,
                                              const float* __restrict__ gate,
                                              float* __restrict__ out) {
    __shared__ __align__(16) u16 Ol[32 * 128];   // O tile, chunk-XOR swizzled
    int blk = blockIdx.x;
    int b = blk >> 7, sb = (blk & 127) * 32;
    int t = threadIdx.x, w = t >> 6, l = t & 63, lc = l & 15, lg = l >> 4;
    float g = gate[0];

    {
        int sl = t >> 3, ci = t & 7;
        int h = ci >> 2, d0 = (ci & 3) * 16;
        size_t rp0 = ((size_t)(b * 2 + h) << 12) + sb + sl;
        float2 e[KSPLIT];
        float ms = -INFINITY;
#pragma unroll
        for (int k = 0; k < KSPLIT; k++) {
            e[k] = ml[rp0 + (size_t)k * 16384];
            ms = fmaxf(ms, e[k].x);
        }
        float den = 0.f, c[KSPLIT];
#pragma unroll
        for (int k = 0; k < KSPLIT; k++) {
            c[k] = exp2f(e[k].x - ms);
            den += c[k] * e[k].y;
        }
        float inv = 1.0f / den;
#pragma unroll
        for (int half = 0; half < 2; half++) {
            float acc[8];
#pragma unroll
            for (int j = 0; j < 8; j++) acc[j] = 0.f;
#pragma unroll
            for (int k = 0; k < KSPLIT; k++) {
                short8 a = ld8(Op + (rp0 + (size_t)k * 16384) * 64 + d0 + half * 8);
#pragma unroll
                for (int j = 0; j < 8; j++) acc[j] += c[k] * b2f((u16)a[j]);
            }
            short8 ov;
#pragma unroll
            for (int j = 0; j < 8; j++) ov[j] = (short)f2b(acc[j] * inv);
            int chunk = ci * 2 + half;
            *reinterpret_cast<short8*>(&Ol[sl * 128 + ((chunk ^ (sl & 7)) << 3)]) = ov;
        }
    }
    __syncthreads();

    // out = O @ Wc^T + bc + gate*x
    short8 af[4];
#pragma unroll
    for (int ks = 0; ks < 4; ks++)
        af[ks] = ld8(Wc + (w * 16 + lc) * 128 + ks * 32 + lg * 8);

#pragma unroll
    for (int st = 0; st < 2; st++) {
        f32x4 acc = {0.f, 0.f, 0.f, 0.f};
#pragma unroll
        for (int ks = 0; ks < 4; ks++) {
            short8 bfr = ld8(&Ol[(st * 16 + lc) * 128 + (((ks * 4 + lg) ^ (lc & 7)) << 3)]);
            acc = MFMA(af[ks], bfr, acc);
        }
#pragma unroll
        for (int r = 0; r < 4; r++) {
            int co = w * 16 + lg * 4 + r;
            int s = sb + st * 16 + lc;
            size_t idx = ((size_t)b * 64 + co) * SEQ + s;
            out[idx] = acc[r] + bc[co] + g * x[idx];
        }
    }
}

extern "C" void kernel_launch(void* const* d_in, const int* in_sizes, int n_in,
                              void* d_out, int out_size, void* d_ws, size_t ws_size,
                              hipStream_t stream) {
    const float* x    = (const float*)d_in[0];
    const float* Wcp  = (const float*)d_in[1];
    const float* bcp  = (const float*)d_in[2];
    const float* Wq   = (const float*)d_in[3];
    const float* Wk   = (const float*)d_in[4];
    const float* Wv   = (const float*)d_in[5];
    const float* Wo   = (const float*)d_in[6];
    const float* bo   = (const float*)d_in[7];
    const float* Wout = (const float*)d_in[8];
    const float* bout = (const float*)d_in[9];
    const float* pos  = (const float*)d_in[10];
    const float* gate = (const float*)d_in[11];

    char* ws = (char*)d_ws;
    float2* mlp  = (float2*)(ws);                        // [0,1MB)  [8][4][4096] float2
    u16*    Qb   = (u16*)(ws + (2u << 20));              // [2,4) MB  (b,h,s,d) bf16
    u16*    Kb   = (u16*)(ws + (4u << 20));              // [4,6) MB
    u16*    Vt   = (u16*)(ws + (6u << 20));              // [6,8) MB  (b,h,d,s) bf16
    u16*    Wc   = (u16*)(ws + (10u << 20));             // 16 KB
    float*  bc   = (float*)(ws + (10u << 20) + 16384);   // 256 B
    u16*    Wcp_b = (u16*)(ws + (10u << 20) + 32768);    // 16 KB
    u16*    Wq_b  = (u16*)(ws + (10u << 20) + 49152);    // 32 KB
    u16*    Wk_b  = (u16*)(ws + (10u << 20) + 81920);    // 32 KB
    u16*    Wv_b  = (u16*)(ws + (10u << 20) + 114688);   // 32 KB
    u16*    Opb  = (u16*)(ws + (10u << 20) + (512u << 10)); // [10.5,26.5) MB bf16 partials
    float* out = (float*)d_out;

    hipLaunchKernelGGL(k_prep, dim3(257), dim3(256), 0, stream,
                       Wo, bo, Wout, bout, Wcp, Wq, Wk, Wv,
                       Wc, bc, Wcp_b, Wq_b, Wk_b, Wv_b);
    hipLaunchKernelGGL(k_front, dim3(256), dim3(256), 0, stream,
                       x, Wcp_b, bcp, pos, Wq_b, Wk_b, Wv_b, Qb, Kb, Vt);
    hipLaunchKernelGGL(k_attn, dim3(256 * KSPLIT), dim3(256), 0, stream, Qb, Kb, Vt, Opb, mlp);
    hipLaunchKernelGGL(k_back, dim3(256), dim3(256), 0, stream, Opb, mlp, Wc, bc, x, gate, out);
}

// Round 9
// 60.470 us; speedup vs baseline: 3.4041x; 1.0223x over previous
//
#include <hip/hip_runtime.h>
#include <hip/hip_bf16.h>
#include <cstdint>

typedef unsigned short u16;
typedef __attribute__((ext_vector_type(8))) short short8;
typedef __attribute__((ext_vector_type(8))) float f32x8;
typedef __attribute__((ext_vector_type(4))) float f32x4;

#define MFMA(a, b, c) __builtin_amdgcn_mfma_f32_16x16x32_bf16((a), (b), (c), 0, 0, 0)

// B=2, S=4096, E=128, NH=2, HD=64, CIN=64, COUT=64
#define SEQ 4096
#define KSPLIT 8
#define NTILE (SEQ / KSPLIT / 32)   // 32-key tiles per block = 16

static __device__ __forceinline__ float b2f(u16 u) {
    union { float f; uint32_t i; } c; c.i = ((uint32_t)u) << 16; return c.f;
}
static __device__ __forceinline__ u16 f2b(float f) {
    union { float f; uint32_t i; } c; c.f = f;
    uint32_t r = c.i + 0x7FFF + ((c.i >> 16) & 1);   // RNE f32->bf16
    return (u16)(r >> 16);
}
static __device__ __forceinline__ short8 ld8(const u16* p) {
    return *reinterpret_cast<const short8*>(p);
}
// pack two f32 -> bf16x2 word (lo = a, hi = b), RNE
static __device__ __forceinline__ uint32_t pk2(float a, float b) {
    uint32_t r;
    asm("v_cvt_pk_bf16_f32 %0, %1, %2" : "=v"(r) : "v"(a), "v"(b));
    return r;
}
// async global->LDS: per-lane global src, wave-uniform LDS base + lane*16B
static __device__ __forceinline__ void gld16(const u16* g, u16* l) {
    __builtin_amdgcn_global_load_lds(
        (const __attribute__((address_space(1))) unsigned int*)g,
        (__attribute__((address_space(3))) unsigned int*)l, 16, 0, 0);
}

// ---- K0: Wc = Wout @ Wo (bf16), bc = bo @ Wout^T + bout (f32); weights f32->bf16 ----
__global__ void k_prep(const float* __restrict__ Wo, const float* __restrict__ bo,
                       const float* __restrict__ Wout, const float* __restrict__ bout,
                       const float* __restrict__ Wcp, const float* __restrict__ Wq,
                       const float* __restrict__ Wk, const float* __restrict__ Wv,
                       u16* __restrict__ Wc, float* __restrict__ bc,
                       u16* __restrict__ Wcp_b, u16* __restrict__ Wq_b,
                       u16* __restrict__ Wk_b, u16* __restrict__ Wv_b) {
    int idx = blockIdx.x * 256 + threadIdx.x;
    if (idx < 8192) {
        int co = idx >> 7, e = idx & 127;
        float s = 0.f;
        for (int k = 0; k < 128; k++)
            s += Wout[co * 128 + k] * Wo[k * 128 + e];
        Wc[idx] = f2b(s);
    } else if (idx < 8256) {
        int co = idx - 8192;
        float s = bout[co];
        for (int k = 0; k < 128; k++)
            s += bo[k] * Wout[co * 128 + k];
        bc[co] = s;
    } else if (idx < 16448) {
        int i = idx - 8256;  Wcp_b[i] = f2b(Wcp[i]);
    } else if (idx < 32832) {
        int i = idx - 16448; Wq_b[i] = f2b(Wq[i]);
    } else if (idx < 49216) {
        int i = idx - 32832; Wk_b[i] = f2b(Wk[i]);
    } else if (idx < 65600) {
        int i = idx - 49216; Wv_b[i] = f2b(Wv[i]);
    }
}

// ---- K1: FUSED embed+qkv. Grid 256 = b*128 + sblk (32 s-rows each). ----
__global__ __launch_bounds__(256) void k_front(const float* __restrict__ x,
                                               const u16* __restrict__ Wcp,
                                               const float* __restrict__ bcp,
                                               const float* __restrict__ pos,
                                               const u16* __restrict__ Wq,
                                               const u16* __restrict__ Wk,
                                               const u16* __restrict__ Wv,
                                               u16* __restrict__ Q, u16* __restrict__ K,
                                               u16* __restrict__ V) {
    __shared__ __align__(16) u16 xT[32][72];     // [s][c] transposed input
    __shared__ __align__(16) u16 xfl[32 * 128];  // xf tile, chunk-XOR swizzled
    int blk = blockIdx.x;
    int b = blk >> 7, sb = (blk & 127) * 32;
    int t = threadIdx.x, w = t >> 6, l = t & 63, lc = l & 15, lg = l >> 4;

    {
        int c = t & 63, so = t >> 6;
        const float* src = x + ((size_t)b * 64 + c) * SEQ + sb + so * 8;
        f32x8 a0 = *reinterpret_cast<const f32x8*>(src);
#pragma unroll
        for (int j = 0; j < 8; j++) xT[so * 8 + j][c] = f2b(a0[j]);
    }
    __syncthreads();

    // phase 1: xf = xT @ Wcp^T + bcp + pos  -> swizzled LDS
    {
        int rt = w >> 1, eh = w & 1;
        short8 af[2];
        af[0] = ld8(&xT[rt * 16 + lc][lg * 8]);
        af[1] = ld8(&xT[rt * 16 + lc][32 + lg * 8]);
#pragma unroll
        for (int et = 0; et < 4; et++) {
            int nt = eh * 4 + et;
            f32x4 acc = {0.f, 0.f, 0.f, 0.f};
#pragma unroll
            for (int ks = 0; ks < 2; ks++) {
                short8 bfr = ld8(Wcp + (nt * 16 + lc) * 64 + ks * 32 + lg * 8);
                acc = MFMA(af[ks], bfr, acc);
            }
            int e = nt * 16 + lc;
            float be = bcp[e];
            int chunk = e >> 3;
#pragma unroll
            for (int r = 0; r < 4; r++) {
                int sl = rt * 16 + lg * 4 + r;
                float v = acc[r] + be + pos[(size_t)(sb + sl) * 128 + e];
                xfl[sl * 128 + ((chunk ^ (sl & 7)) << 3) + (e & 7)] = f2b(v);
            }
        }
    }
    __syncthreads();

    // phase 2: Q/K/V from LDS xf
    {
        int st = w & 1, hr = w >> 1;
        short8 afq[4];
#pragma unroll
        for (int ks = 0; ks < 4; ks++)
            afq[ks] = ld8(&xfl[(st * 16 + lc) * 128 + (((ks * 4 + lg) ^ (lc & 7)) << 3)]);

        const float qscl = 0.18033688011112042f;  // 0.125 * log2(e)
#pragma unroll
        for (int qk = 0; qk < 2; qk++) {
            const u16* W = qk ? Wk : Wq;
            u16* dst = qk ? K : Q;
#pragma unroll
            for (int et = 0; et < 4; et++) {
                int nt = hr * 4 + et;
                f32x4 acc = {0.f, 0.f, 0.f, 0.f};
#pragma unroll
                for (int ks = 0; ks < 4; ks++) {
                    short8 bfr = ld8(W + (nt * 16 + lc) * 128 + ks * 32 + lg * 8);
                    acc = MFMA(afq[ks], bfr, acc);
                }
                int e = nt * 16 + lc, h = e >> 6, d = e & 63;
                float scl = qk ? 1.0f : qscl;
#pragma unroll
                for (int r = 0; r < 4; r++) {
                    int sr = sb + st * 16 + lg * 4 + r;
                    dst[(((size_t)b * 2 + h) * SEQ + sr) * 64 + d] = f2b(acc[r] * scl);
                }
            }
        }
        // V^T: A = Wv rows (d), B = xf rows (s) -> coalesced V^T stores
#pragma unroll
        for (int et = 0; et < 4; et++) {
            int nt = hr * 4 + et;
            f32x4 acc = {0.f, 0.f, 0.f, 0.f};
            short8 wv[4];
#pragma unroll
            for (int ks = 0; ks < 4; ks++)
                wv[ks] = ld8(Wv + (nt * 16 + lc) * 128 + ks * 32 + lg * 8);
#pragma unroll
            for (int ks = 0; ks < 4; ks++)
                acc = MFMA(wv[ks], afq[ks], acc);
#pragma unroll
            for (int r = 0; r < 4; r++) {
                int d = nt * 16 + lg * 4 + r, h = d >> 6, dd = d & 63;
                V[((size_t)(b * 2 + h) * 64 + dd) * SEQ + sb + st * 16 + lc] = f2b(acc[r]);
            }
        }
    }
}

// ---- K2: flash attention, split-K=8, QBLK=128 (wave owns 32 q = 2 B-frags).
//  K/V fragments shared across both q-halves -> per-score LDS and addressing halved.
//  Grid 1024 = 4 blocks/CU. Swapped QK^T, lane-local deferred max, ls via ones-MFMA. ----
__global__ __launch_bounds__(256, 4) void k_attn(const u16* __restrict__ Q,
                                                 const u16* __restrict__ K,
                                                 const u16* __restrict__ Vg,
                                                 u16* __restrict__ Op,
                                                 float2* __restrict__ ml) {
    __shared__ __align__(16) u16 Klds[2][2048];   // [key 32][d 64], chunk^(key&7)
    __shared__ __align__(16) u16 Vlds[2][2048];   // [d 64][key 32], chunk^s(d)
    __shared__ __align__(16) u16 Pl[4][32][32];   // per-wave P [q 32][key 32], chunk^s(q)
    int blk = blockIdx.x;
    int split = blk >> 7, bh = (blk >> 5) & 3, qb = (blk & 31) * 128;
    int kbase = split * (SEQ / KSPLIT);
    const u16* Qp = Q + (size_t)bh * SEQ * 64;
    const u16* Kp = K + (size_t)bh * SEQ * 64;
    const u16* Vp = Vg + (size_t)bh * SEQ * 64;   // (d, s)
    int t = threadIdx.x, w = t >> 6, l = t & 63, lc = l & 15, lg = l >> 4;
    uint32_t* plw = (uint32_t*)&Pl[w][0][0];      // per-wave, row stride 16 u32
    const u16* plu = &Pl[w][0][0];

    // staging sources (pre-swizzled; LDS dest linear = base + lane*16B)
    const u16* kSrc = Kp + (size_t)(kbase + w * 8 + (l >> 3)) * 64 + (((l & 7) ^ (l >> 3)) << 3);
    int vrow = w * 16 + (l >> 2);
    int vswz = (l & 3) ^ ((((l >> 2) & 3) + (l >> 4)) & 3);
    const u16* vSrc = Vp + (size_t)vrow * SEQ + kbase + (vswz << 3);

    // Q B-frags: [ks][qh], q col = qb + w*32 + qh*16 + lc
    short8 qa[2][2];
#pragma unroll
    for (int ks = 0; ks < 2; ks++)
#pragma unroll
        for (int qh = 0; qh < 2; qh++)
            qa[ks][qh] = ld8(Qp + (size_t)(qb + w * 32 + qh * 16 + lc) * 64 + ks * 32 + lg * 8);

    short8 onesb;   // bf16 1.0 B-fragment for row-sum MFMA
#pragma unroll
    for (int i = 0; i < 8; i++) onesb[i] = (short)0x3F80;

    f32x4 oacc[2][4], lsacc[2];
#pragma unroll
    for (int qh = 0; qh < 2; qh++) {
        lsacc[qh] = (f32x4){0.f, 0.f, 0.f, 0.f};
#pragma unroll
        for (int dt = 0; dt < 4; dt++) oacc[qh][dt] = (f32x4){0.f, 0.f, 0.f, 0.f};
    }
    float m[2] = {-INFINITY, -INFINITY};

    int c0 = (lg ^ (lc & 7)) * 8;              // K-frag swizzled offset (8-chunk rows)
    int sp = (((lc & 3) + (lc >> 2)) & 3);     // row-swizzle key for P and V (4-chunk rows)
    int cv = (lg ^ sp) * 8;                    // V-frag / P-read swizzled offset

#define STAGE(buf, tt) do {                                       \
        gld16(kSrc + (size_t)(tt) * 2048, &Klds[buf][w * 512]);   \
        gld16(vSrc + (tt) * 32,           &Vlds[buf][w * 512]);   \
    } while (0)

    STAGE(0, 0);
    __syncthreads();

#pragma unroll 2
    for (int tt = 0; tt < NTILE; tt++) {
        int cur = tt & 1;
        if (tt + 1 < NTILE) STAGE(cur ^ 1, tt + 1);

        const u16* kb = Klds[cur];
        const u16* vb = Vlds[cur];

        // scores: sc[nt][qh][r] = S[key = nt*16+lg*4+r][q = qb+w*32+qh*16+lc]
        f32x4 sc[2][2];
#pragma unroll
        for (int nt = 0; nt < 2; nt++) {
            short8 kf0 = ld8(kb + (nt * 16 + lc) * 64 + c0);
            short8 kf1 = ld8(kb + (nt * 16 + lc) * 64 + (c0 ^ 32));
#pragma unroll
            for (int qh = 0; qh < 2; qh++) {
                f32x4 a = {0.f, 0.f, 0.f, 0.f};
                a = MFMA(kf0, qa[0][qh], a);
                a = MFMA(kf1, qa[1][qh], a);
                sc[nt][qh] = a;
            }
        }

        // lane-local max per q-half
        float mx[2];
#pragma unroll
        for (int qh = 0; qh < 2; qh++)
            mx[qh] = fmaxf(
                fmaxf(fmaxf(sc[0][qh][0], sc[0][qh][1]), fmaxf(sc[0][qh][2], sc[0][qh][3])),
                fmaxf(fmaxf(sc[1][qh][0], sc[1][qh][1]), fmaxf(sc[1][qh][2], sc[1][qh][3])));

        // deferred rescale (log2 units, threshold 8)
        if (__any((mx[0] - m[0] > 8.f) || (mx[1] - m[1] > 8.f))) {
#pragma unroll
            for (int qh = 0; qh < 2; qh++) {
                float mr = fmaxf(mx[qh], __shfl_xor(mx[qh], 16));
                mr = fmaxf(mr, __shfl_xor(mr, 32));
                float mn = fmaxf(m[qh], mr);
                float corr = exp2f(m[qh] - mn);   // first tile: exp2(-inf)=0
#pragma unroll
                for (int r = 0; r < 4; r++) {
                    float cr = __shfl(corr, lg * 4 + r);
#pragma unroll
                    for (int dt = 0; dt < 4; dt++) oacc[qh][dt][r] *= cr;
                    lsacc[qh][r] *= cr;
                }
                m[qh] = mn;
            }
        }

        // exp2 + pack + store P (row q = qh*16+lc, chunk (nt*2+(lg>>1))^sp, half lg&1)
#pragma unroll
        for (int qh = 0; qh < 2; qh++) {
            int rowb = (qh * 16 + lc) * 16 + (lg & 1) * 2;
#pragma unroll
            for (int nt = 0; nt < 2; nt++) {
                uint2 u;
                u.x = pk2(exp2f(sc[nt][qh][0] - m[qh]), exp2f(sc[nt][qh][1] - m[qh]));
                u.y = pk2(exp2f(sc[nt][qh][2] - m[qh]), exp2f(sc[nt][qh][3] - m[qh]));
                int cc = (nt * 2 + (lg >> 1)) ^ sp;
                *reinterpret_cast<uint2*>(&plw[rowb + cc * 4]) = u;
            }
        }

        // O += P @ V ; ls += P @ ones. V-frags shared across q-halves.
        short8 pa0 = ld8(plu + (lc) * 32 + cv);
        short8 pa1 = ld8(plu + (16 + lc) * 32 + cv);
        lsacc[0] = MFMA(pa0, onesb, lsacc[0]);
        lsacc[1] = MFMA(pa1, onesb, lsacc[1]);
#pragma unroll
        for (int dt = 0; dt < 4; dt++) {
            short8 vf = ld8(vb + (dt * 16 + lc) * 32 + cv);
            oacc[0][dt] = MFMA(pa0, vf, oacc[0][dt]);
            oacc[1][dt] = MFMA(pa1, vf, oacc[1][dt]);
        }
        __syncthreads();
    }
#undef STAGE

    // epilogue: unnormalized bf16 partials + per-row (m, ls)
    size_t rowbase = (size_t)(split * 4 + bh) * SEQ + qb + w * 32;
#pragma unroll
    for (int qh = 0; qh < 2; qh++)
#pragma unroll
        for (int dt = 0; dt < 4; dt++)
#pragma unroll
            for (int r = 0; r < 4; r++)
                Op[(rowbase + qh * 16 + lg * 4 + r) * 64 + dt * 16 + lc] = f2b(oacc[qh][dt][r]);
    float mr[2][4];
#pragma unroll
    for (int qh = 0; qh < 2; qh++)
#pragma unroll
        for (int r = 0; r < 4; r++) mr[qh][r] = __shfl(m[qh], lg * 4 + r);
    if (lc == 0) {
#pragma unroll
        for (int qh = 0; qh < 2; qh++)
#pragma unroll
            for (int r = 0; r < 4; r++) {
                float2 v; v.x = mr[qh][r]; v.y = lsacc[qh][r];
                ml[rowbase + qh * 16 + lg * 4 + r] = v;
            }
    }
}

// ---- K3: FUSED comb+out. Grid 256 = b*128 + sblk (32 s-rows). 8-way merge. ----
__global__ __launch_bounds__(256) void k_back(const u16* __restrict__ Op,
                                              const float2* __restrict__ ml,
                                              const u16* __restrict__ Wc,
                                              const float* __restrict__ bc,
                                              const float* __restrict__ x,
                                              const float* __restrict__ gate,
                                              float* __restrict__ out) {
    __shared__ __align__(16) u16 Ol[32 * 128];   // O tile, chunk-XOR swizzled
    int blk = blockIdx.x;
    int b = blk >> 7, sb = (blk & 127) * 32;
    int t = threadIdx.x, w = t >> 6, l = t & 63, lc = l & 15, lg = l >> 4;
    float g = gate[0];

    {
        int sl = t >> 3, ci = t & 7;
        int h = ci >> 2, d0 = (ci & 3) * 16;
        size_t rp0 = ((size_t)(b * 2 + h) << 12) + sb + sl;
        float2 e[KSPLIT];
        float ms = -INFINITY;
#pragma unroll
        for (int k = 0; k < KSPLIT; k++) {
            e[k] = ml[rp0 + (size_t)k * 16384];
            ms = fmaxf(ms, e[k].x);
        }
        float den = 0.f, c[KSPLIT];
#pragma unroll
        for (int k = 0; k < KSPLIT; k++) {
            c[k] = exp2f(e[k].x - ms);
            den += c[k] * e[k].y;
        }
        float inv = 1.0f / den;
#pragma unroll
        for (int half = 0; half < 2; half++) {
            float acc[8];
#pragma unroll
            for (int j = 0; j < 8; j++) acc[j] = 0.f;
#pragma unroll
            for (int k = 0; k < KSPLIT; k++) {
                short8 a = ld8(Op + (rp0 + (size_t)k * 16384) * 64 + d0 + half * 8);
#pragma unroll
                for (int j = 0; j < 8; j++) acc[j] += c[k] * b2f((u16)a[j]);
            }
            short8 ov;
#pragma unroll
            for (int j = 0; j < 8; j++) ov[j] = (short)f2b(acc[j] * inv);
            int chunk = ci * 2 + half;
            *reinterpret_cast<short8*>(&Ol[sl * 128 + ((chunk ^ (sl & 7)) << 3)]) = ov;
        }
    }
    __syncthreads();

    // out = O @ Wc^T + bc + gate*x
    short8 af[4];
#pragma unroll
    for (int ks = 0; ks < 4; ks++)
        af[ks] = ld8(Wc + (w * 16 + lc) * 128 + ks * 32 + lg * 8);

#pragma unroll
    for (int st = 0; st < 2; st++) {
        f32x4 acc = {0.f, 0.f, 0.f, 0.f};
#pragma unroll
        for (int ks = 0; ks < 4; ks++) {
            short8 bfr = ld8(&Ol[(st * 16 + lc) * 128 + (((ks * 4 + lg) ^ (lc & 7)) << 3)]);
            acc = MFMA(af[ks], bfr, acc);
        }
#pragma unroll
        for (int r = 0; r < 4; r++) {
            int co = w * 16 + lg * 4 + r;
            int s = sb + st * 16 + lc;
            size_t idx = ((size_t)b * 64 + co) * SEQ + s;
            out[idx] = acc[r] + bc[co] + g * x[idx];
        }
    }
}

extern "C" void kernel_launch(void* const* d_in, const int* in_sizes, int n_in,
                              void* d_out, int out_size, void* d_ws, size_t ws_size,
                              hipStream_t stream) {
    const float* x    = (const float*)d_in[0];
    const float* Wcp  = (const float*)d_in[1];
    const float* bcp  = (const float*)d_in[2];
    const float* Wq   = (const float*)d_in[3];
    const float* Wk   = (const float*)d_in[4];
    const float* Wv   = (const float*)d_in[5];
    const float* Wo   = (const float*)d_in[6];
    const float* bo   = (const float*)d_in[7];
    const float* Wout = (const float*)d_in[8];
    const float* bout = (const float*)d_in[9];
    const float* pos  = (const float*)d_in[10];
    const float* gate = (const float*)d_in[11];

    char* ws = (char*)d_ws;
    float2* mlp  = (float2*)(ws);                        // [0,1MB)  [8][4][4096] float2
    u16*    Qb   = (u16*)(ws + (2u << 20));              // [2,4) MB  (b,h,s,d) bf16
    u16*    Kb   = (u16*)(ws + (4u << 20));              // [4,6) MB
    u16*    Vt   = (u16*)(ws + (6u << 20));              // [6,8) MB  (b,h,d,s) bf16
    u16*    Wc   = (u16*)(ws + (10u << 20));             // 16 KB
    float*  bc   = (float*)(ws + (10u << 20) + 16384);   // 256 B
    u16*    Wcp_b = (u16*)(ws + (10u << 20) + 32768);    // 16 KB
    u16*    Wq_b  = (u16*)(ws + (10u << 20) + 49152);    // 32 KB
    u16*    Wk_b  = (u16*)(ws + (10u << 20) + 81920);    // 32 KB
    u16*    Wv_b  = (u16*)(ws + (10u << 20) + 114688);   // 32 KB
    u16*    Opb  = (u16*)(ws + (10u << 20) + (512u << 10)); // [10.5,26.5) MB bf16 partials
    float* out = (float*)d_out;

    hipLaunchKernelGGL(k_prep, dim3(257), dim3(256), 0, stream,
                       Wo, bo, Wout, bout, Wcp, Wq, Wk, Wv,
                       Wc, bc, Wcp_b, Wq_b, Wk_b, Wv_b);
    hipLaunchKernelGGL(k_front, dim3(256), dim3(256), 0, stream,
                       x, Wcp_b, bcp, pos, Wq_b, Wk_b, Wv_b, Qb, Kb, Vt);
    hipLaunchKernelGGL(k_attn, dim3(1024), dim3(256), 0, stream, Qb, Kb, Vt, Opb, mlp);
    hipLaunchKernelGGL(k_back, dim3(256), dim3(256), 0, stream, Opb, mlp, Wc, bc, x, gate, out);
}